// Round 1
// baseline (846.550 us; speedup 1.0000x reference)
//
#include <hip/hip_runtime.h>

typedef __bf16 bf16_t;
typedef __bf16 bf16x8 __attribute__((ext_vector_type(8)));
typedef float floatx4 __attribute__((ext_vector_type(4)));

#define B_    128
#define H_    14
#define HW_   196
#define C_    768
#define NH_   12
#define HD_   64
#define BH_   1536
#define M_    25088
#define NQKV_ 2304
#define KDIM_ 768
#define VPAD_ 208   // padded key dim for v^T rows (16B-aligned rows)
#define KPAD_ 208   // padded key dim for score tiles (13 * 16)
#define PPAD_ 224   // padded key dim for P / vT LDS (7 * 32 for MFMA K-steps)

// ---------------------------------------------------------------- cast x -> bf16
__global__ __launch_bounds__(256) void cast_x_kernel(const float* __restrict__ in,
                                                     bf16_t* __restrict__ out) {
    size_t i = ((size_t)blockIdx.x * 256 + threadIdx.x) * 8;
    float4 a = *(const float4*)(in + i);
    float4 b = *(const float4*)(in + i + 4);
    bf16x8 v;
    v[0] = (bf16_t)a.x; v[1] = (bf16_t)a.y; v[2] = (bf16_t)a.z; v[3] = (bf16_t)a.w;
    v[4] = (bf16_t)b.x; v[5] = (bf16_t)b.y; v[6] = (bf16_t)b.z; v[7] = (bf16_t)b.w;
    *(bf16x8*)(out + i) = v;
}

// ------------------------------------------- transpose + cast weight (rows x cols) -> (cols x rows)
__global__ __launch_bounds__(256) void transpose_cast_kernel(const float* __restrict__ in,
                                                             bf16_t* __restrict__ out,
                                                             int rows, int cols) {
    __shared__ float tile[32][33];
    int c0 = blockIdx.x * 32, r0 = blockIdx.y * 32;
    for (int i = threadIdx.y; i < 32; i += 8) {
        int r = r0 + i, c = c0 + threadIdx.x;
        if (r < rows && c < cols) tile[i][threadIdx.x] = in[(size_t)r * cols + c];
    }
    __syncthreads();
    for (int i = threadIdx.y; i < 32; i += 8) {
        int orow = c0 + i;            // output row = input col
        int oc   = r0 + threadIdx.x;  // output col = input row
        if (orow < cols && oc < rows)
            out[(size_t)orow * rows + oc] = (bf16_t)tile[threadIdx.x][i];
    }
}

// ---------------------------------------------------------------- shared GEMM core
// A: M x 768 row-major bf16.  Bt: N x 768 row-major bf16 (i.e. B transposed).
// 128x128 block tile, BK=32, 256 threads = 4 waves in 2x2, each wave 64x64 (4x4 MFMA tiles).
__device__ __forceinline__ void gemm128_compute(const bf16_t* __restrict__ A,
                                                const bf16_t* __restrict__ Bt,
                                                int m0, int n0,
                                                floatx4 acc[4][4],
                                                bf16_t (*As)[32], bf16_t (*Bs)[32]) {
    const int tid  = threadIdx.x;
    const int lane = tid & 63, wave = tid >> 6;
    const int wm = (wave & 1) << 6, wn = (wave >> 1) << 6;
    const int lrow = lane & 15, quad = lane >> 4;

    #pragma unroll
    for (int i = 0; i < 4; i++)
        #pragma unroll
        for (int j = 0; j < 4; j++) acc[i][j] = (floatx4){0.f, 0.f, 0.f, 0.f};

    const int r0 = tid >> 2;          // 0..63
    const int c0 = (tid & 3) * 8;     // 0,8,16,24
    const bf16_t* Abase0 = A  + (size_t)(m0 + r0) * KDIM_ + c0;
    const bf16_t* Abase1 = A  + (size_t)(m0 + r0 + 64) * KDIM_ + c0;
    const bf16_t* Bbase0 = Bt + (size_t)(n0 + r0) * KDIM_ + c0;
    const bf16_t* Bbase1 = Bt + (size_t)(n0 + r0 + 64) * KDIM_ + c0;

    for (int k0 = 0; k0 < KDIM_; k0 += 32) {
        __syncthreads();
        *(uint4*)&As[r0][c0]      = *(const uint4*)(Abase0 + k0);
        *(uint4*)&As[r0 + 64][c0] = *(const uint4*)(Abase1 + k0);
        *(uint4*)&Bs[r0][c0]      = *(const uint4*)(Bbase0 + k0);
        *(uint4*)&Bs[r0 + 64][c0] = *(const uint4*)(Bbase1 + k0);
        __syncthreads();

        bf16x8 af[4], bfr[4];
        #pragma unroll
        for (int i = 0; i < 4; i++) af[i]  = *(const bf16x8*)&As[wm + i * 16 + lrow][quad * 8];
        #pragma unroll
        for (int j = 0; j < 4; j++) bfr[j] = *(const bf16x8*)&Bs[wn + j * 16 + lrow][quad * 8];
        #pragma unroll
        for (int i = 0; i < 4; i++)
            #pragma unroll
            for (int j = 0; j < 4; j++)
                acc[i][j] = __builtin_amdgcn_mfma_f32_16x16x32_bf16(af[i], bfr[j], acc[i][j], 0, 0, 0);
    }
}

// ---------------------------------------------------------------- QKV GEMM + scatter epilogue
__global__ __launch_bounds__(256) void qkv_gemm_kernel(const bf16_t* __restrict__ A,
                                                       const bf16_t* __restrict__ Bt,
                                                       const float* __restrict__ bias,
                                                       bf16_t* __restrict__ qb,
                                                       bf16_t* __restrict__ kb,
                                                       bf16_t* __restrict__ vtb) {
    __shared__ __align__(16) bf16_t As[128][32];
    __shared__ __align__(16) bf16_t Bs[128][32];
    const int m0 = blockIdx.x * 128, n0 = blockIdx.y * 128;
    floatx4 acc[4][4];
    gemm128_compute(A, Bt, m0, n0, acc, As, Bs);

    const int lane = threadIdx.x & 63, wave = threadIdx.x >> 6;
    const int wm = (wave & 1) << 6, wn = (wave >> 1) << 6;
    const int lrow = lane & 15, quad = lane >> 4;
    #pragma unroll
    for (int j = 0; j < 4; j++) {
        int n = n0 + wn + j * 16 + lrow;      // 0..2303
        float bv = bias[n];
        int sel = n / C_;                     // 0=q 1=k 2=v
        int nc = n - sel * C_;
        int nh = nc >> 6, hd = nc & 63;
        #pragma unroll
        for (int i = 0; i < 4; i++) {
            #pragma unroll
            for (int r = 0; r < 4; r++) {
                int m = m0 + wm + i * 16 + quad * 4 + r;   // 0..25087
                int b = m / HW_, t = m - b * HW_;
                int head = b * NH_ + nh;
                float v = acc[i][j][r] + bv;
                if (sel == 0)      qb[((size_t)head * HW_ + t) * HD_ + hd] = (bf16_t)v;
                else if (sel == 1) kb[((size_t)head * HW_ + t) * HD_ + hd] = (bf16_t)v;
                else               vtb[((size_t)head * HD_ + hd) * VPAD_ + t] = (bf16_t)v;
            }
        }
    }
}

// ---------------------------------------------------------------- proj GEMM + bias -> fp32 out
__global__ __launch_bounds__(256) void proj_gemm_kernel(const bf16_t* __restrict__ A,
                                                        const bf16_t* __restrict__ Bt,
                                                        const float* __restrict__ bias,
                                                        float* __restrict__ out) {
    __shared__ __align__(16) bf16_t As[128][32];
    __shared__ __align__(16) bf16_t Bs[128][32];
    const int m0 = blockIdx.x * 128, n0 = blockIdx.y * 128;
    floatx4 acc[4][4];
    gemm128_compute(A, Bt, m0, n0, acc, As, Bs);

    const int lane = threadIdx.x & 63, wave = threadIdx.x >> 6;
    const int wm = (wave & 1) << 6, wn = (wave >> 1) << 6;
    const int lrow = lane & 15, quad = lane >> 4;
    #pragma unroll
    for (int j = 0; j < 4; j++) {
        int n = n0 + wn + j * 16 + lrow;
        float bv = bias[n];
        #pragma unroll
        for (int i = 0; i < 4; i++) {
            #pragma unroll
            for (int r = 0; r < 4; r++) {
                int m = m0 + wm + i * 16 + quad * 4 + r;
                out[(size_t)m * C_ + n] = acc[i][j][r] + bv;
            }
        }
    }
}

// ---------------------------------------------------------------- fused attention
// grid (7, 1536): blockIdx.x = query tile (32 q rows), blockIdx.y = head (b*12+nh)
__global__ __launch_bounds__(256) void attn_kernel(const bf16_t* __restrict__ qb,
                                                   const bf16_t* __restrict__ kb,
                                                   const bf16_t* __restrict__ vtb,
                                                   const float* __restrict__ rph,
                                                   const float* __restrict__ rpw,
                                                   bf16_t* __restrict__ aout) {
    const int qt = blockIdx.x;
    const int head = blockIdx.y;
    const int bb = head / NH_, nh = head - bb * NH_;
    const int q0 = qt * 32;
    const int tid = threadIdx.x;
    const int lane = tid & 63, wave = tid >> 6;
    const int lrow = lane & 15, quad = lane >> 4;

    __shared__ __align__(16) bf16_t qs[32][64];
    __shared__ __align__(16) bf16_t kv_u[HD_ * PPAD_];           // union: ks[208][64] / vTs[64][224]
    __shared__ __align__(16) float  sS[32][KPAD_];
    __shared__ __align__(16) bf16_t pb[32][PPAD_];
    __shared__ float relh[32][14];
    __shared__ float relw[32][14];
    __shared__ float rowinv[32];

    bf16_t (*ks)[64]    = (bf16_t(*)[64])kv_u;
    bf16_t (*vTs)[PPAD_] = (bf16_t(*)[PPAD_])kv_u;

    bf16x8 z;
    #pragma unroll
    for (int e = 0; e < 8; e++) z[e] = (bf16_t)0.f;

    // ---- load q tile (zero-pad invalid rows)
    {
        int row = tid >> 3, col = (tid & 7) * 8;
        int t = q0 + row;
        if (t < HW_) *(bf16x8*)&qs[row][col] = *(const bf16x8*)(qb + ((size_t)head * HW_ + t) * HD_ + col);
        else         *(bf16x8*)&qs[row][col] = z;
    }
    // ---- load all keys (208 rows, zero pad)
    for (int idx = tid * 8; idx < KPAD_ * HD_; idx += 2048) {
        int row = idx >> 6, col = idx & 63;
        if (row < HW_) *(bf16x8*)&ks[row][col] = *(const bf16x8*)(kb + ((size_t)head * HW_ + row) * HD_ + col);
        else           *(bf16x8*)&ks[row][col] = z;
    }
    __syncthreads();

    // ---- rel_h / rel_w:  rel[qi][kk] = sum_c q[qi][c] * rel_pos[(h_or_w - kk + 13)][c]
    for (int u = tid; u < 2 * 32 * 14; u += 256) {
        int which = u / 448, rem = u - which * 448;
        int qi = rem / 14, kk = rem - qi * 14;
        float s = 0.f;
        int t = q0 + qi;
        if (t < HW_) {
            int h = t / 14, w = t - h * 14;
            int coord = (which == 0 ? h : w) - kk + 13;
            const float* tbl = (which == 0 ? rph : rpw) + (size_t)coord * HD_;
            #pragma unroll 8
            for (int c = 0; c < HD_; c++) s += (float)qs[qi][c] * tbl[c];
        }
        if (which == 0) relh[qi][kk] = s;
        else            relw[qi][kk] = s;
    }
    __syncthreads();

    // ---- S = scale * q@k^T + rel   (13 n-tiles x 2 m-tiles split over 4 waves)
    const int mi = wave & 1;
    for (int jt = (wave >> 1); jt < 13; jt += 2) {
        floatx4 a4 = (floatx4){0.f, 0.f, 0.f, 0.f};
        #pragma unroll
        for (int kk = 0; kk < 2; kk++) {
            bf16x8 af  = *(const bf16x8*)&qs[mi * 16 + lrow][kk * 32 + quad * 8];
            bf16x8 bf8 = *(const bf16x8*)&ks[jt * 16 + lrow][kk * 32 + quad * 8];
            a4 = __builtin_amdgcn_mfma_f32_16x16x32_bf16(af, bf8, a4, 0, 0, 0);
        }
        int n = jt * 16 + lrow;
        if (n < HW_) {
            int kh = n / 14, kw = n - kh * 14;
            #pragma unroll
            for (int r = 0; r < 4; r++) {
                int qi = mi * 16 + quad * 4 + r;
                sS[qi][n] = a4[r] * 0.125f + relh[qi][kh] + relw[qi][kw];
            }
        }
    }
    __syncthreads();

    // ---- softmax (8 threads per row, 28 cols each; cols 196..223 land exactly in g==7)
    {
        int qi = tid >> 3, g = tid & 7;
        int nbase = g * 28;
        float mx = -1e30f;
        for (int u = 0; u < 28; u++) {
            int n = nbase + u;
            if (n < HW_) mx = fmaxf(mx, sS[qi][n]);
        }
        #pragma unroll
        for (int off = 1; off < 8; off <<= 1) mx = fmaxf(mx, __shfl_xor(mx, off, 8));
        float sum = 0.f;
        for (int u = 0; u < 28; u++) {
            int n = nbase + u;
            float e = 0.f;
            if (n < HW_) { e = __expf(sS[qi][n] - mx); sum += e; }
            pb[qi][n] = (bf16_t)e;   // unnormalized; pad cols get exact 0
        }
        #pragma unroll
        for (int off = 1; off < 8; off <<= 1) sum += __shfl_xor(sum, off, 8);
        if (g == 0) rowinv[qi] = 1.f / sum;
    }
    __syncthreads();

    // ---- load v^T (overwrites ks union region; zero pad cols >= 208)
    for (int idx = tid * 8; idx < HD_ * PPAD_; idx += 2048) {
        int row = idx / PPAD_, col = idx - row * PPAD_;
        if (col < VPAD_) *(bf16x8*)&vTs[row][col] = *(const bf16x8*)(vtb + ((size_t)head * HD_ + row) * VPAD_ + col);
        else             *(bf16x8*)&vTs[row][col] = z;
    }
    __syncthreads();

    // ---- O = P @ V  (2 m-tiles x 4 n-tiles over 4 waves; K = 224 = 7 steps)
    const int j2 = (wave >> 1) * 2;
    #pragma unroll
    for (int jj = 0; jj < 2; jj++) {
        int jt = j2 + jj;
        floatx4 a4 = (floatx4){0.f, 0.f, 0.f, 0.f};
        #pragma unroll
        for (int kk = 0; kk < 7; kk++) {
            bf16x8 af  = *(const bf16x8*)&pb[mi * 16 + lrow][kk * 32 + quad * 8];
            bf16x8 bf8 = *(const bf16x8*)&vTs[jt * 16 + lrow][kk * 32 + quad * 8];
            a4 = __builtin_amdgcn_mfma_f32_16x16x32_bf16(af, bf8, a4, 0, 0, 0);
        }
        int col = nh * HD_ + jt * 16 + lrow;
        #pragma unroll
        for (int r = 0; r < 4; r++) {
            int m = mi * 16 + quad * 4 + r;
            int t = q0 + m;
            if (t < HW_)
                aout[((size_t)bb * HW_ + t) * C_ + col] = (bf16_t)(a4[r] * rowinv[m]);
        }
    }
}

// ---------------------------------------------------------------- launcher
extern "C" void kernel_launch(void* const* d_in, const int* in_sizes, int n_in,
                              void* d_out, int out_size, void* d_ws, size_t ws_size,
                              hipStream_t stream) {
    const float* hs    = (const float*)d_in[0];
    const float* wqkv  = (const float*)d_in[1];
    const float* bqkv  = (const float*)d_in[2];
    const float* rph   = (const float*)d_in[3];
    const float* rpw   = (const float*)d_in[4];
    const float* wproj = (const float*)d_in[5];
    const float* bproj = (const float*)d_in[6];
    float* out = (float*)d_out;

    char* ws = (char*)d_ws;
    // layout (bytes):
    //   [0)            x_bf (M*C*2 = 38,535,168)  -- reused as aout after QKV GEMM consumes x
    //   [38,535,168)   wqkvT (2304*768*2)
    //   [42,074,112)   wprojT (768*768*2)
    //   [43,253,760)   q  (1536*196*64*2)
    //   [81,788,928)   k  (1536*196*64*2)
    //   [120,324,096)  vT (1536*64*208*2 = 40,894,464)  -> total 161,218,560
    bf16_t* x_bf   = (bf16_t*)(ws + 0);
    bf16_t* aout   = x_bf;
    bf16_t* wqkvT  = (bf16_t*)(ws + 38535168);
    bf16_t* wprojT = (bf16_t*)(ws + 42074112);
    bf16_t* qb     = (bf16_t*)(ws + 43253760);
    bf16_t* kb     = (bf16_t*)(ws + 81788928);
    bf16_t* vtb    = (bf16_t*)(ws + 120324096);

    cast_x_kernel<<<9408, 256, 0, stream>>>(hs, x_bf);
    transpose_cast_kernel<<<dim3(72, 24), dim3(32, 8), 0, stream>>>(wqkv, wqkvT, 768, 2304);
    transpose_cast_kernel<<<dim3(24, 24), dim3(32, 8), 0, stream>>>(wproj, wprojT, 768, 768);
    qkv_gemm_kernel<<<dim3(196, 18), 256, 0, stream>>>(x_bf, wqkvT, bqkv, qb, kb, vtb);
    attn_kernel<<<dim3(7, 1536), 256, 0, stream>>>(qb, kb, vtb, rph, rpw, aout);
    proj_gemm_kernel<<<dim3(196, 6), 256, 0, stream>>>(aout, wprojT, bproj, out);
}

// Round 2
// 591.560 us; speedup vs baseline: 1.4310x; 1.4310x over previous
//
#include <hip/hip_runtime.h>

typedef __bf16 bf16_t;
typedef __bf16 bf16x8 __attribute__((ext_vector_type(8)));
typedef float floatx4 __attribute__((ext_vector_type(4)));

#define B_    128
#define H_    14
#define HW_   196
#define C_    768
#define NH_   12
#define HD_   64
#define M_    25088
#define NQKV_ 2304
#define KDIM_ 768
#define VPAD_ 208   // v^T global row length (16B-aligned)
#define KSTR  72    // qs/ks/rT LDS row stride in bf16 (144B breaks 128B bank aliasing)
#define SSTR  212   // sS LDS row stride in fp32 (212 mod 32 = 20 -> 2-way on stores = free)
#define PSTR  224   // pb / vTs LDS row stride in bf16 (7 k-steps of 32)

// ---------------------------------------------------------------- async 16B global->LDS
__device__ __forceinline__ void async_cp16(const void* g, void* l) {
    __builtin_amdgcn_global_load_lds((const __attribute__((address_space(1))) void*)g,
                                     (__attribute__((address_space(3))) void*)l, 16, 0, 0);
}

// ---------------------------------------------------------------- cast x -> bf16
__global__ __launch_bounds__(256) void cast_x_kernel(const float* __restrict__ in,
                                                     bf16_t* __restrict__ out) {
    size_t i = ((size_t)blockIdx.x * 256 + threadIdx.x) * 8;
    float4 a = *(const float4*)(in + i);
    float4 b = *(const float4*)(in + i + 4);
    bf16x8 v;
    v[0] = (bf16_t)a.x; v[1] = (bf16_t)a.y; v[2] = (bf16_t)a.z; v[3] = (bf16_t)a.w;
    v[4] = (bf16_t)b.x; v[5] = (bf16_t)b.y; v[6] = (bf16_t)b.z; v[7] = (bf16_t)b.w;
    *(bf16x8*)(out + i) = v;
}

// ------------------------------------------- transpose + cast weight (rows x cols) -> (cols x rows)
__global__ __launch_bounds__(256) void transpose_cast_kernel(const float* __restrict__ in,
                                                             bf16_t* __restrict__ out,
                                                             int rows, int cols) {
    __shared__ float tile[32][33];
    int c0 = blockIdx.x * 32, r0 = blockIdx.y * 32;
    for (int i = threadIdx.y; i < 32; i += 8) {
        int r = r0 + i, c = c0 + threadIdx.x;
        if (r < rows && c < cols) tile[i][threadIdx.x] = in[(size_t)r * cols + c];
    }
    __syncthreads();
    for (int i = threadIdx.y; i < 32; i += 8) {
        int orow = c0 + i;            // output row = input col
        int oc   = r0 + threadIdx.x;  // output col = input row
        if (orow < cols && oc < rows)
            out[(size_t)orow * rows + oc] = (bf16_t)tile[threadIdx.x][i];
    }
}

// ---------------------------------------------------------------- shared GEMM core
// A: M x 768 row-major bf16.  Bt: N x 768 row-major bf16 (i.e. B transposed).
// 128x128 block tile, BK=32, 256 threads = 4 waves in 2x2, each wave 64x64 (4x4 MFMA tiles).
// Staging via global_load_lds width=16: LDS dest of thread tid is exactly 16B*tid
// (wave-uniform base + lane*16 -- the required pattern).
__device__ __forceinline__ void gemm128_compute(const bf16_t* __restrict__ A,
                                                const bf16_t* __restrict__ Bt,
                                                int m0, int n0,
                                                floatx4 acc[4][4],
                                                bf16_t (*As)[32], bf16_t (*Bs)[32]) {
    const int tid  = threadIdx.x;
    const int lane = tid & 63, wave = tid >> 6;
    const int wm = (wave & 1) << 6, wn = (wave >> 1) << 6;
    const int lrow = lane & 15, quad = lane >> 4;

    #pragma unroll
    for (int i = 0; i < 4; i++)
        #pragma unroll
        for (int j = 0; j < 4; j++) acc[i][j] = (floatx4){0.f, 0.f, 0.f, 0.f};

    const int r0 = tid >> 2;          // 0..63
    const int c0 = (tid & 3) * 8;     // 0,8,16,24
    const bf16_t* Abase0 = A  + (size_t)(m0 + r0) * KDIM_ + c0;
    const bf16_t* Abase1 = A  + (size_t)(m0 + r0 + 64) * KDIM_ + c0;
    const bf16_t* Bbase0 = Bt + (size_t)(n0 + r0) * KDIM_ + c0;
    const bf16_t* Bbase1 = Bt + (size_t)(n0 + r0 + 64) * KDIM_ + c0;

    for (int k0 = 0; k0 < KDIM_; k0 += 32) {
        __syncthreads();
        async_cp16(Abase0 + k0, &As[r0][c0]);
        async_cp16(Abase1 + k0, &As[r0 + 64][c0]);
        async_cp16(Bbase0 + k0, &Bs[r0][c0]);
        async_cp16(Bbase1 + k0, &Bs[r0 + 64][c0]);
        __syncthreads();

        bf16x8 af[4], bfr[4];
        #pragma unroll
        for (int i = 0; i < 4; i++) af[i]  = *(const bf16x8*)&As[wm + i * 16 + lrow][quad * 8];
        #pragma unroll
        for (int j = 0; j < 4; j++) bfr[j] = *(const bf16x8*)&Bs[wn + j * 16 + lrow][quad * 8];
        #pragma unroll
        for (int i = 0; i < 4; i++)
            #pragma unroll
            for (int j = 0; j < 4; j++)
                acc[i][j] = __builtin_amdgcn_mfma_f32_16x16x32_bf16(af[i], bfr[j], acc[i][j], 0, 0, 0);
    }
}

// ---------------------------------------------------------------- QKV GEMM + scatter epilogue
__global__ __launch_bounds__(256) void qkv_gemm_kernel(const bf16_t* __restrict__ A,
                                                       const bf16_t* __restrict__ Bt,
                                                       const float* __restrict__ bias,
                                                       bf16_t* __restrict__ qb,
                                                       bf16_t* __restrict__ kb,
                                                       bf16_t* __restrict__ vtb) {
    __shared__ __align__(16) bf16_t As[128][32];
    __shared__ __align__(16) bf16_t Bs[128][32];
    const int m0 = blockIdx.x * 128, n0 = blockIdx.y * 128;
    floatx4 acc[4][4];
    gemm128_compute(A, Bt, m0, n0, acc, As, Bs);

    const int lane = threadIdx.x & 63, wave = threadIdx.x >> 6;
    const int wm = (wave & 1) << 6, wn = (wave >> 1) << 6;
    const int lrow = lane & 15, quad = lane >> 4;
    #pragma unroll
    for (int j = 0; j < 4; j++) {
        int n = n0 + wn + j * 16 + lrow;      // 0..2303
        float bv = bias[n];
        int sel = n / C_;                     // 0=q 1=k 2=v
        int nc = n - sel * C_;
        int nh = nc >> 6, hd = nc & 63;
        #pragma unroll
        for (int i = 0; i < 4; i++) {
            #pragma unroll
            for (int r = 0; r < 4; r++) {
                int m = m0 + wm + i * 16 + quad * 4 + r;   // 0..25087
                int b = m / HW_, t = m - b * HW_;
                int head = b * NH_ + nh;
                float v = acc[i][j][r] + bv;
                if (sel == 0)      qb[((size_t)head * HW_ + t) * HD_ + hd] = (bf16_t)v;
                else if (sel == 1) kb[((size_t)head * HW_ + t) * HD_ + hd] = (bf16_t)v;
                else               vtb[((size_t)head * HD_ + hd) * VPAD_ + t] = (bf16_t)v;
            }
        }
    }
}

// ---------------------------------------------------------------- proj GEMM + bias -> fp32 out
__global__ __launch_bounds__(256) void proj_gemm_kernel(const bf16_t* __restrict__ A,
                                                        const bf16_t* __restrict__ Bt,
                                                        const float* __restrict__ bias,
                                                        float* __restrict__ out) {
    __shared__ __align__(16) bf16_t As[128][32];
    __shared__ __align__(16) bf16_t Bs[128][32];
    const int m0 = blockIdx.x * 128, n0 = blockIdx.y * 128;
    floatx4 acc[4][4];
    gemm128_compute(A, Bt, m0, n0, acc, As, Bs);

    const int lane = threadIdx.x & 63, wave = threadIdx.x >> 6;
    const int wm = (wave & 1) << 6, wn = (wave >> 1) << 6;
    const int lrow = lane & 15, quad = lane >> 4;
    #pragma unroll
    for (int j = 0; j < 4; j++) {
        int n = n0 + wn + j * 16 + lrow;
        float bv = bias[n];
        #pragma unroll
        for (int i = 0; i < 4; i++) {
            #pragma unroll
            for (int r = 0; r < 4; r++) {
                int m = m0 + wm + i * 16 + quad * 4 + r;
                out[(size_t)m * C_ + n] = acc[i][j][r] + bv;
            }
        }
    }
}

// ---------------------------------------------------------------- fused attention
// grid (7, 1536): blockIdx.x = query tile (32 q rows), blockIdx.y = head (b*12+nh)
// rel_h/rel_w computed as MFMA: QR[qi][l] = q[qi] . rel_pos[l], then gathered by coord.
__global__ __launch_bounds__(256) void attn_kernel(const bf16_t* __restrict__ qb,
                                                   const bf16_t* __restrict__ kb,
                                                   const bf16_t* __restrict__ vtb,
                                                   const float* __restrict__ rph,
                                                   const float* __restrict__ rpw,
                                                   bf16_t* __restrict__ aout) {
    const int qt = blockIdx.x;
    const int head = blockIdx.y;
    const int bb = head / NH_, nh = head - bb * NH_;
    const int q0 = qt * 32;
    const int tid = threadIdx.x;
    const int lane = tid & 63, wave = tid >> 6;
    const int lrow = lane & 15, quad = lane >> 4;

    __shared__ __align__(16) bf16_t qs[32][KSTR];            // 4608 B
    __shared__ __align__(16) bf16_t kvu[208 * KSTR];         // 29952 B: ks[208][72] U vTs[64][224]
    __shared__ __align__(16) char   sSu[32 * SSTR * 4];      // 27136 B: sS[32][212] U rT[64][72] U pb[32][224]
    __shared__ float QRh[32][33];
    __shared__ float QRw[32][33];
    __shared__ float rowinv[32];

    float  (*sS)[SSTR]  = (float(*)[SSTR])sSu;
    bf16_t (*rT)[KSTR]  = (bf16_t(*)[KSTR])sSu;              // rows 0..31 = rph, 32..63 = rpw
    bf16_t (*pb)[PSTR]  = (bf16_t(*)[PSTR])sSu;
    bf16_t (*ks)[KSTR]  = (bf16_t(*)[KSTR])kvu;
    bf16_t (*vTs)[PSTR] = (bf16_t(*)[PSTR])kvu;

    bf16x8 z;
    #pragma unroll
    for (int e = 0; e < 8; e++) z[e] = (bf16_t)0.f;

    // ---- phase 0: load q tile, rel tables (bf16, padded rows zero), keys
    {
        int row = tid >> 3, col = (tid & 7) * 8;
        int t = q0 + row;
        *(bf16x8*)&qs[row][col] =
            (t < HW_) ? *(const bf16x8*)(qb + ((size_t)head * HW_ + t) * HD_ + col) : z;
    }
    #pragma unroll
    for (int t2 = 0; t2 < 2; t2++) {
        int u = tid * 2 + t2;              // 0..511
        int which = u >> 8, rem = u & 255;
        int l = rem >> 3, c = (rem & 7) * 8;
        bf16x8 v = z;
        if (l < 27) {
            const float* src = (which ? rpw : rph) + (size_t)l * HD_ + c;
            float4 a = *(const float4*)src;
            float4 b = *(const float4*)(src + 4);
            v[0] = (bf16_t)a.x; v[1] = (bf16_t)a.y; v[2] = (bf16_t)a.z; v[3] = (bf16_t)a.w;
            v[4] = (bf16_t)b.x; v[5] = (bf16_t)b.y; v[6] = (bf16_t)b.z; v[7] = (bf16_t)b.w;
        }
        *(bf16x8*)&rT[which * 32 + l][c] = v;
    }
    for (int v8 = tid; v8 < 208 * 8; v8 += 256) {
        int row = v8 >> 3, col = (v8 & 7) * 8;
        *(bf16x8*)&ks[row][col] =
            (row < HW_) ? *(const bf16x8*)(kb + ((size_t)head * HW_ + row) * HD_ + col) : z;
    }
    __syncthreads();

    // ---- phase 1: QR tables via MFMA (8 tasks = which x mi x ni; 2 per wave)
    #pragma unroll
    for (int t2 = 0; t2 < 2; t2++) {
        int task = wave * 2 + t2;
        int which = task >> 2, mi2 = (task >> 1) & 1, ni = task & 1;
        floatx4 a4 = (floatx4){0.f, 0.f, 0.f, 0.f};
        #pragma unroll
        for (int kk = 0; kk < 2; kk++) {
            bf16x8 af  = *(const bf16x8*)&qs[mi2 * 16 + lrow][kk * 32 + quad * 8];
            bf16x8 bf8 = *(const bf16x8*)&rT[which * 32 + ni * 16 + lrow][kk * 32 + quad * 8];
            a4 = __builtin_amdgcn_mfma_f32_16x16x32_bf16(af, bf8, a4, 0, 0, 0);
        }
        int l = ni * 16 + lrow;
        if (l < 27) {
            float (*QR)[33] = which ? QRw : QRh;
            #pragma unroll
            for (int r = 0; r < 4; r++) QR[mi2 * 16 + quad * 4 + r][l] = a4[r];
        }
    }
    __syncthreads();   // QR ready; rT staging region now dead -> sS writable

    // ---- phase 2: S = 0.125*q@kT + gathered rel
    const int mi = wave & 1;
    int hq[4], wq[4];
    #pragma unroll
    for (int r = 0; r < 4; r++) {
        int t = q0 + mi * 16 + quad * 4 + r;
        hq[r] = t / 14; wq[r] = t - hq[r] * 14;
    }
    for (int jt = (wave >> 1); jt < 13; jt += 2) {
        floatx4 a4 = (floatx4){0.f, 0.f, 0.f, 0.f};
        #pragma unroll
        for (int kk = 0; kk < 2; kk++) {
            bf16x8 af  = *(const bf16x8*)&qs[mi * 16 + lrow][kk * 32 + quad * 8];
            bf16x8 bf8 = *(const bf16x8*)&ks[jt * 16 + lrow][kk * 32 + quad * 8];
            a4 = __builtin_amdgcn_mfma_f32_16x16x32_bf16(af, bf8, a4, 0, 0, 0);
        }
        int n = jt * 16 + lrow;
        if (n < HW_) {
            int kh = n / 14, kw = n - kh * 14;
            #pragma unroll
            for (int r = 0; r < 4; r++) {
                int qi = mi * 16 + quad * 4 + r;
                sS[qi][n] = a4[r] * 0.125f + QRh[qi][hq[r] - kh + 13] + QRw[qi][wq[r] - kw + 13];
            }
        }
    }
    __syncthreads();

    // ---- phase 3a: load v^T into kvu (ks is dead after phase 2)
    #pragma unroll
    for (int i = 0; i < 7; i++) {
        int v8 = tid + i * 256;            // 0..1791
        int row = v8 / 28, c8 = v8 - row * 28, col = c8 * 8;
        bf16x8 v = (col < VPAD_)
            ? *(const bf16x8*)(vtb + ((size_t)head * HD_ + row) * VPAD_ + col) : z;
        *(bf16x8*)&vTs[row][col] = v;
    }

    // ---- phase 3b: softmax (8 threads/row, 28 cols each; float4 reads, reg staging)
    {
        int qi = tid >> 3, g = tid & 7, nb = g * 28;
        float ev[28];
        #pragma unroll
        for (int u4 = 0; u4 < 7; u4++) {
            float4 f = *(const float4*)&sS[qi][nb + u4 * 4];
            ev[u4 * 4 + 0] = f.x; ev[u4 * 4 + 1] = f.y;
            ev[u4 * 4 + 2] = f.z; ev[u4 * 4 + 3] = f.w;
        }
        float mx = -1e30f;
        #pragma unroll
        for (int u = 0; u < 28; u++) if (nb + u < HW_) mx = fmaxf(mx, ev[u]);
        #pragma unroll
        for (int off = 1; off < 8; off <<= 1) mx = fmaxf(mx, __shfl_xor(mx, off, 8));
        float sum = 0.f;
        #pragma unroll
        for (int u = 0; u < 28; u++) {
            float e = (nb + u < HW_) ? __expf(ev[u] - mx) : 0.f;
            ev[u] = e; sum += e;
        }
        #pragma unroll
        for (int off = 1; off < 8; off <<= 1) sum += __shfl_xor(sum, off, 8);
        if (g == 0) rowinv[qi] = 1.f / sum;
        __syncthreads();   // all sS reads complete before pb overwrites the region
        #pragma unroll
        for (int u = 0; u < 28; u++) pb[qi][nb + u] = (bf16_t)ev[u];
    }
    __syncthreads();

    // ---- phase 4: O = P @ V  (2 mi x 4 jt over 4 waves; K = 224 = 7 steps)
    const int j2 = (wave >> 1) * 2;
    #pragma unroll
    for (int jj = 0; jj < 2; jj++) {
        int jt = j2 + jj;
        floatx4 a4 = (floatx4){0.f, 0.f, 0.f, 0.f};
        #pragma unroll
        for (int kk = 0; kk < 7; kk++) {
            bf16x8 af  = *(const bf16x8*)&pb[mi * 16 + lrow][kk * 32 + quad * 8];
            bf16x8 bf8 = *(const bf16x8*)&vTs[jt * 16 + lrow][kk * 32 + quad * 8];
            a4 = __builtin_amdgcn_mfma_f32_16x16x32_bf16(af, bf8, a4, 0, 0, 0);
        }
        int col = nh * HD_ + jt * 16 + lrow;
        #pragma unroll
        for (int r = 0; r < 4; r++) {
            int m = mi * 16 + quad * 4 + r;
            int t = q0 + m;
            if (t < HW_)
                aout[((size_t)bb * HW_ + t) * C_ + col] = (bf16_t)(a4[r] * rowinv[m]);
        }
    }
}

// ---------------------------------------------------------------- launcher
extern "C" void kernel_launch(void* const* d_in, const int* in_sizes, int n_in,
                              void* d_out, int out_size, void* d_ws, size_t ws_size,
                              hipStream_t stream) {
    const float* hs    = (const float*)d_in[0];
    const float* wqkv  = (const float*)d_in[1];
    const float* bqkv  = (const float*)d_in[2];
    const float* rph   = (const float*)d_in[3];
    const float* rpw   = (const float*)d_in[4];
    const float* wproj = (const float*)d_in[5];
    const float* bproj = (const float*)d_in[6];
    float* out = (float*)d_out;

    char* ws = (char*)d_ws;
    bf16_t* x_bf   = (bf16_t*)(ws + 0);          // 38,535,168 B; reused as aout
    bf16_t* aout   = x_bf;
    bf16_t* wqkvT  = (bf16_t*)(ws + 38535168);
    bf16_t* wprojT = (bf16_t*)(ws + 42074112);
    bf16_t* qb     = (bf16_t*)(ws + 43253760);
    bf16_t* kb     = (bf16_t*)(ws + 81788928);
    bf16_t* vtb    = (bf16_t*)(ws + 120324096);  // total 161,218,560

    cast_x_kernel<<<9408, 256, 0, stream>>>(hs, x_bf);
    transpose_cast_kernel<<<dim3(72, 24), dim3(32, 8), 0, stream>>>(wqkv, wqkvT, 768, 2304);
    transpose_cast_kernel<<<dim3(24, 24), dim3(32, 8), 0, stream>>>(wproj, wprojT, 768, 768);
    qkv_gemm_kernel<<<dim3(196, 18), 256, 0, stream>>>(x_bf, wqkvT, bqkv, qb, kb, vtb);
    attn_kernel<<<dim3(7, 1536), 256, 0, stream>>>(qb, kb, vtb, rph, rpw, aout);
    proj_gemm_kernel<<<dim3(196, 6), 256, 0, stream>>>(aout, wprojT, bproj, out);
}

// Round 3
// 510.030 us; speedup vs baseline: 1.6598x; 1.1599x over previous
//
#include <hip/hip_runtime.h>

typedef __bf16 bf16_t;
typedef __bf16 bf16x8 __attribute__((ext_vector_type(8)));
typedef float floatx4 __attribute__((ext_vector_type(4)));

#define B_    128
#define H_    14
#define HW_   196
#define C_    768
#define NH_   12
#define HD_   64
#define M_    25088
#define NQKV_ 2304
#define KDIM_ 768
#define BK_   64    // K-tile: 12 iterations over K=768, 32 MFMAs per barrier
#define VPAD_ 208   // v^T global row length (16B-aligned)
#define KSTR  72    // qs/ks/rT LDS row stride in bf16 (144B breaks 128B bank aliasing)
#define SSTR  212   // sS LDS row stride in fp32
#define PSTR  224   // pb / vTs LDS row stride in bf16 (7 k-steps of 32)

// ---------------------------------------------------------------- async 16B global->LDS
__device__ __forceinline__ void async_cp16(const void* g, void* l) {
    __builtin_amdgcn_global_load_lds((const __attribute__((address_space(1))) void*)g,
                                     (__attribute__((address_space(3))) void*)l, 16, 0, 0);
}

// ---------------------------------------------------------------- cast x -> bf16
__global__ __launch_bounds__(256) void cast_x_kernel(const float* __restrict__ in,
                                                     bf16_t* __restrict__ out) {
    size_t i = ((size_t)blockIdx.x * 256 + threadIdx.x) * 8;
    float4 a = *(const float4*)(in + i);
    float4 b = *(const float4*)(in + i + 4);
    bf16x8 v;
    v[0] = (bf16_t)a.x; v[1] = (bf16_t)a.y; v[2] = (bf16_t)a.z; v[3] = (bf16_t)a.w;
    v[4] = (bf16_t)b.x; v[5] = (bf16_t)b.y; v[6] = (bf16_t)b.z; v[7] = (bf16_t)b.w;
    *(bf16x8*)(out + i) = v;
}

// ------------------------------------------- transpose + cast weight (rows x cols) -> (cols x rows)
__global__ __launch_bounds__(256) void transpose_cast_kernel(const float* __restrict__ in,
                                                             bf16_t* __restrict__ out,
                                                             int rows, int cols) {
    __shared__ float tile[32][33];
    int c0 = blockIdx.x * 32, r0 = blockIdx.y * 32;
    for (int i = threadIdx.y; i < 32; i += 8) {
        int r = r0 + i, c = c0 + threadIdx.x;
        if (r < rows && c < cols) tile[i][threadIdx.x] = in[(size_t)r * cols + c];
    }
    __syncthreads();
    for (int i = threadIdx.y; i < 32; i += 8) {
        int orow = c0 + i;            // output row = input col
        int oc   = r0 + threadIdx.x;  // output col = input row
        if (orow < cols && oc < rows)
            out[(size_t)orow * rows + oc] = (bf16_t)tile[threadIdx.x][i];
    }
}

// ---------------------------------------------------------------- shared GEMM core
// A: M x 768 row-major bf16.  Bt: N x 768 row-major bf16 (i.e. B transposed).
// 128x128 block tile, BK=64, 256 threads = 4 waves in 2x2, each wave 64x64 (4x4 MFMA tiles).
// Staging via global_load_lds width=16; LDS dest of instruction i is 16B*(tid + i*256)
// (wave-uniform base + lane*16). Column-chunk XOR swizzle (cc ^ row&7) keeps the
// b128 fragment reads at the 8-lane/bank floor despite the 128B row stride.
__device__ __forceinline__ void gemm128_compute(const bf16_t* __restrict__ A,
                                                const bf16_t* __restrict__ Bt,
                                                int m0, int n0,
                                                floatx4 acc[4][4],
                                                bf16_t (*As)[BK_], bf16_t (*Bs)[BK_]) {
    const int tid  = threadIdx.x;
    const int lane = tid & 63, wave = tid >> 6;
    const int wm = (wave & 1) << 6, wn = (wave >> 1) << 6;
    const int lrow = lane & 15, quad = lane >> 4;

    #pragma unroll
    for (int i = 0; i < 4; i++)
        #pragma unroll
        for (int j = 0; j < 4; j++) acc[i][j] = (floatx4){0.f, 0.f, 0.f, 0.f};

    const int sr = tid >> 3;        // staging base row 0..31 (+ i*32)
    const int cc = tid & 7;         // LDS column chunk (16B units)

    for (int k0 = 0; k0 < KDIM_; k0 += BK_) {
        __syncthreads();
        #pragma unroll
        for (int i = 0; i < 4; i++) {
            int row  = sr + i * 32;
            int scol = ((cc ^ (row & 7)) * 8);      // swizzled source k-chunk
            async_cp16(A  + (size_t)(m0 + row) * KDIM_ + k0 + scol, &As[row][cc * 8]);
            async_cp16(Bt + (size_t)(n0 + row) * KDIM_ + k0 + scol, &Bs[row][cc * 8]);
        }
        __syncthreads();

        #pragma unroll
        for (int kh = 0; kh < 2; kh++) {
            bf16x8 af[4], bfr[4];
            #pragma unroll
            for (int i = 0; i < 4; i++) {
                int rw = wm + i * 16 + lrow;
                af[i] = *(const bf16x8*)&As[rw][((kh * 4 + quad) ^ (rw & 7)) * 8];
            }
            #pragma unroll
            for (int j = 0; j < 4; j++) {
                int rw = wn + j * 16 + lrow;
                bfr[j] = *(const bf16x8*)&Bs[rw][((kh * 4 + quad) ^ (rw & 7)) * 8];
            }
            #pragma unroll
            for (int i = 0; i < 4; i++)
                #pragma unroll
                for (int j = 0; j < 4; j++)
                    acc[i][j] = __builtin_amdgcn_mfma_f32_16x16x32_bf16(af[i], bfr[j], acc[i][j], 0, 0, 0);
        }
    }
}

// ---------------------------------------------------------------- QKV GEMM + scatter epilogue
// 1D grid 3528, L2 swizzle: 4-m-tile chunk (0.8 MB of A) x all 18 n-tiles per group.
__global__ __launch_bounds__(256) void qkv_gemm_kernel(const bf16_t* __restrict__ A,
                                                       const bf16_t* __restrict__ Bt,
                                                       const float* __restrict__ bias,
                                                       bf16_t* __restrict__ qb,
                                                       bf16_t* __restrict__ kb,
                                                       bf16_t* __restrict__ vtb) {
    __shared__ __align__(16) bf16_t As[128][BK_];
    __shared__ __align__(16) bf16_t Bs[128][BK_];
    const int lin = blockIdx.x;
    const int g = lin / 72, r = lin - g * 72;
    const int m0 = (g * 4 + (r & 3)) * 128;
    const int n0 = (r >> 2) * 128;
    floatx4 acc[4][4];
    gemm128_compute(A, Bt, m0, n0, acc, As, Bs);

    const int lane = threadIdx.x & 63, wave = threadIdx.x >> 6;
    const int wm = (wave & 1) << 6, wn = (wave >> 1) << 6;
    const int lrow = lane & 15, quad = lane >> 4;
    #pragma unroll
    for (int j = 0; j < 4; j++) {
        int n = n0 + wn + j * 16 + lrow;      // 0..2303
        float bv = bias[n];
        int sel = n / C_;                     // 0=q 1=k 2=v
        int nc = n - sel * C_;
        int nh = nc >> 6, hd = nc & 63;
        if (sel == 2) {
            // v^T: 4 consecutive t per (i) -> one ushort4 store (196%4==0: never crosses head)
            #pragma unroll
            for (int i = 0; i < 4; i++) {
                int m = m0 + wm + i * 16 + quad * 4;
                int b = m / HW_, t = m - b * HW_;
                int head = b * NH_ + nh;
                ushort4 pk;
                bf16_t h;
                h = (bf16_t)(acc[i][j][0] + bv); pk.x = __builtin_bit_cast(unsigned short, h);
                h = (bf16_t)(acc[i][j][1] + bv); pk.y = __builtin_bit_cast(unsigned short, h);
                h = (bf16_t)(acc[i][j][2] + bv); pk.z = __builtin_bit_cast(unsigned short, h);
                h = (bf16_t)(acc[i][j][3] + bv); pk.w = __builtin_bit_cast(unsigned short, h);
                *(ushort4*)(vtb + ((size_t)head * HD_ + hd) * VPAD_ + t) = pk;
            }
        } else {
            bf16_t* dst = (sel == 0) ? qb : kb;
            #pragma unroll
            for (int i = 0; i < 4; i++) {
                #pragma unroll
                for (int rr = 0; rr < 4; rr++) {
                    int m = m0 + wm + i * 16 + quad * 4 + rr;
                    int b = m / HW_, t = m - b * HW_;
                    int head = b * NH_ + nh;
                    dst[((size_t)head * HW_ + t) * HD_ + hd] = (bf16_t)(acc[i][j][rr] + bv);
                }
            }
        }
    }
}

// ---------------------------------------------------------------- proj GEMM + bias -> fp32 out
// 1D grid 1176, same 4-m-tile chunk swizzle over 6 n-tiles.
__global__ __launch_bounds__(256) void proj_gemm_kernel(const bf16_t* __restrict__ A,
                                                        const bf16_t* __restrict__ Bt,
                                                        const float* __restrict__ bias,
                                                        float* __restrict__ out) {
    __shared__ __align__(16) bf16_t As[128][BK_];
    __shared__ __align__(16) bf16_t Bs[128][BK_];
    const int lin = blockIdx.x;
    const int g = lin / 24, r = lin - g * 24;
    const int m0 = (g * 4 + (r & 3)) * 128;
    const int n0 = (r >> 2) * 128;
    floatx4 acc[4][4];
    gemm128_compute(A, Bt, m0, n0, acc, As, Bs);

    const int lane = threadIdx.x & 63, wave = threadIdx.x >> 6;
    const int wm = (wave & 1) << 6, wn = (wave >> 1) << 6;
    const int lrow = lane & 15, quad = lane >> 4;
    #pragma unroll
    for (int j = 0; j < 4; j++) {
        int n = n0 + wn + j * 16 + lrow;
        float bv = bias[n];
        #pragma unroll
        for (int i = 0; i < 4; i++) {
            #pragma unroll
            for (int rr = 0; rr < 4; rr++) {
                int m = m0 + wm + i * 16 + quad * 4 + rr;
                out[(size_t)m * C_ + n] = acc[i][j][rr] + bv;
            }
        }
    }
}

// ---------------------------------------------------------------- fused attention
// 1D grid 10752. XCD-partition remap: lin&7 selects XCD stream; each XCD runs whole
// heads (7 q-tiles back-to-back) so k/v stay hot in that XCD's L2.
__global__ __launch_bounds__(256) void attn_kernel(const bf16_t* __restrict__ qb,
                                                   const bf16_t* __restrict__ kb,
                                                   const bf16_t* __restrict__ vtb,
                                                   const float* __restrict__ rph,
                                                   const float* __restrict__ rpw,
                                                   bf16_t* __restrict__ aout) {
    const int lin = blockIdx.x;
    const int task = (lin & 7) * 1344 + (lin >> 3);
    const int head = task / 7;
    const int qt = task - head * 7;
    const int bb = head / NH_, nh = head - bb * NH_;
    const int q0 = qt * 32;
    const int tid = threadIdx.x;
    const int lane = tid & 63, wave = tid >> 6;
    const int lrow = lane & 15, quad = lane >> 4;

    __shared__ __align__(16) bf16_t qs[32][KSTR];            // 4608 B
    __shared__ __align__(16) bf16_t kvu[208 * KSTR];         // 29952 B: ks[208][72] U vTs[64][224]
    __shared__ __align__(16) char   sSu[32 * SSTR * 4];      // 27136 B: sS[32][212] U rT[64][72] U pb[32][224]
    __shared__ float QRh[32][33];
    __shared__ float QRw[32][33];
    __shared__ float rowinv[32];

    float  (*sS)[SSTR]  = (float(*)[SSTR])sSu;
    bf16_t (*rT)[KSTR]  = (bf16_t(*)[KSTR])sSu;              // rows 0..31 = rph, 32..63 = rpw
    bf16_t (*pb)[PSTR]  = (bf16_t(*)[PSTR])sSu;
    bf16_t (*ks)[KSTR]  = (bf16_t(*)[KSTR])kvu;
    bf16_t (*vTs)[PSTR] = (bf16_t(*)[PSTR])kvu;

    bf16x8 z;
    #pragma unroll
    for (int e = 0; e < 8; e++) z[e] = (bf16_t)0.f;

    // ---- phase 0: load q tile, rel tables (bf16, padded rows zero), keys
    {
        int row = tid >> 3, col = (tid & 7) * 8;
        int t = q0 + row;
        *(bf16x8*)&qs[row][col] =
            (t < HW_) ? *(const bf16x8*)(qb + ((size_t)head * HW_ + t) * HD_ + col) : z;
    }
    #pragma unroll
    for (int t2 = 0; t2 < 2; t2++) {
        int u = tid * 2 + t2;              // 0..511
        int which = u >> 8, rem = u & 255;
        int l = rem >> 3, c = (rem & 7) * 8;
        bf16x8 v = z;
        if (l < 27) {
            const float* src = (which ? rpw : rph) + (size_t)l * HD_ + c;
            float4 a = *(const float4*)src;
            float4 b = *(const float4*)(src + 4);
            v[0] = (bf16_t)a.x; v[1] = (bf16_t)a.y; v[2] = (bf16_t)a.z; v[3] = (bf16_t)a.w;
            v[4] = (bf16_t)b.x; v[5] = (bf16_t)b.y; v[6] = (bf16_t)b.z; v[7] = (bf16_t)b.w;
        }
        *(bf16x8*)&rT[which * 32 + l][c] = v;
    }
    for (int v8 = tid; v8 < 208 * 8; v8 += 256) {
        int row = v8 >> 3, col = (v8 & 7) * 8;
        *(bf16x8*)&ks[row][col] =
            (row < HW_) ? *(const bf16x8*)(kb + ((size_t)head * HW_ + row) * HD_ + col) : z;
    }
    __syncthreads();

    // ---- phase 1: QR tables via MFMA (8 tasks = which x mi x ni; 2 per wave)
    #pragma unroll
    for (int t2 = 0; t2 < 2; t2++) {
        int tsk = wave * 2 + t2;
        int which = tsk >> 2, mi2 = (tsk >> 1) & 1, ni = tsk & 1;
        floatx4 a4 = (floatx4){0.f, 0.f, 0.f, 0.f};
        #pragma unroll
        for (int kk = 0; kk < 2; kk++) {
            bf16x8 af  = *(const bf16x8*)&qs[mi2 * 16 + lrow][kk * 32 + quad * 8];
            bf16x8 bf8 = *(const bf16x8*)&rT[which * 32 + ni * 16 + lrow][kk * 32 + quad * 8];
            a4 = __builtin_amdgcn_mfma_f32_16x16x32_bf16(af, bf8, a4, 0, 0, 0);
        }
        int l = ni * 16 + lrow;
        if (l < 27) {
            float (*QR)[33] = which ? QRw : QRh;
            #pragma unroll
            for (int rr = 0; rr < 4; rr++) QR[mi2 * 16 + quad * 4 + rr][l] = a4[rr];
        }
    }
    __syncthreads();   // QR ready; rT staging region now dead -> sS writable

    // ---- phase 2: S = 0.125*q@kT + gathered rel
    const int mi = wave & 1;
    int hq[4], wq[4];
    #pragma unroll
    for (int rr = 0; rr < 4; rr++) {
        int t = q0 + mi * 16 + quad * 4 + rr;
        hq[rr] = t / 14; wq[rr] = t - hq[rr] * 14;
    }
    for (int jt = (wave >> 1); jt < 13; jt += 2) {
        floatx4 a4 = (floatx4){0.f, 0.f, 0.f, 0.f};
        #pragma unroll
        for (int kk = 0; kk < 2; kk++) {
            bf16x8 af  = *(const bf16x8*)&qs[mi * 16 + lrow][kk * 32 + quad * 8];
            bf16x8 bf8 = *(const bf16x8*)&ks[jt * 16 + lrow][kk * 32 + quad * 8];
            a4 = __builtin_amdgcn_mfma_f32_16x16x32_bf16(af, bf8, a4, 0, 0, 0);
        }
        int n = jt * 16 + lrow;
        if (n < HW_) {
            int kh = n / 14, kw = n - kh * 14;
            #pragma unroll
            for (int rr = 0; rr < 4; rr++) {
                int qi = mi * 16 + quad * 4 + rr;
                sS[qi][n] = a4[rr] * 0.125f + QRh[qi][hq[rr] - kh + 13] + QRw[qi][wq[rr] - kw + 13];
            }
        }
    }
    __syncthreads();

    // ---- phase 3a: load v^T into kvu (ks is dead after phase 2)
    #pragma unroll
    for (int i = 0; i < 7; i++) {
        int v8 = tid + i * 256;            // 0..1791
        int row = v8 / 28, c8 = v8 - row * 28, col = c8 * 8;
        bf16x8 v = (col < VPAD_)
            ? *(const bf16x8*)(vtb + ((size_t)head * HD_ + row) * VPAD_ + col) : z;
        *(bf16x8*)&vTs[row][col] = v;
    }

    // ---- phase 3b: softmax (8 threads/row, 28 cols each; float4 reads, reg staging)
    {
        int qi = tid >> 3, g = tid & 7, nb = g * 28;
        float ev[28];
        #pragma unroll
        for (int u4 = 0; u4 < 7; u4++) {
            float4 f = *(const float4*)&sS[qi][nb + u4 * 4];
            ev[u4 * 4 + 0] = f.x; ev[u4 * 4 + 1] = f.y;
            ev[u4 * 4 + 2] = f.z; ev[u4 * 4 + 3] = f.w;
        }
        float mx = -1e30f;
        #pragma unroll
        for (int u = 0; u < 28; u++) if (nb + u < HW_) mx = fmaxf(mx, ev[u]);
        #pragma unroll
        for (int off = 1; off < 8; off <<= 1) mx = fmaxf(mx, __shfl_xor(mx, off, 8));
        float sum = 0.f;
        #pragma unroll
        for (int u = 0; u < 28; u++) {
            float e = (nb + u < HW_) ? __expf(ev[u] - mx) : 0.f;
            ev[u] = e; sum += e;
        }
        #pragma unroll
        for (int off = 1; off < 8; off <<= 1) sum += __shfl_xor(sum, off, 8);
        if (g == 0) rowinv[qi] = 1.f / sum;
        __syncthreads();   // all sS reads complete before pb overwrites the region
        #pragma unroll
        for (int u = 0; u < 28; u++) pb[qi][nb + u] = (bf16_t)ev[u];
    }
    __syncthreads();

    // ---- phase 4: O = P @ V  (2 mi x 4 jt over 4 waves; K = 224 = 7 steps)
    const int j2 = (wave >> 1) * 2;
    #pragma unroll
    for (int jj = 0; jj < 2; jj++) {
        int jt = j2 + jj;
        floatx4 a4 = (floatx4){0.f, 0.f, 0.f, 0.f};
        #pragma unroll
        for (int kk = 0; kk < 7; kk++) {
            bf16x8 af  = *(const bf16x8*)&pb[mi * 16 + lrow][kk * 32 + quad * 8];
            bf16x8 bf8 = *(const bf16x8*)&vTs[jt * 16 + lrow][kk * 32 + quad * 8];
            a4 = __builtin_amdgcn_mfma_f32_16x16x32_bf16(af, bf8, a4, 0, 0, 0);
        }
        int col = nh * HD_ + jt * 16 + lrow;
        #pragma unroll
        for (int rr = 0; rr < 4; rr++) {
            int m = mi * 16 + quad * 4 + rr;
            int t = q0 + m;
            if (t < HW_)
                aout[((size_t)bb * HW_ + t) * C_ + col] = (bf16_t)(a4[rr] * rowinv[m]);
        }
    }
}

// ---------------------------------------------------------------- launcher
extern "C" void kernel_launch(void* const* d_in, const int* in_sizes, int n_in,
                              void* d_out, int out_size, void* d_ws, size_t ws_size,
                              hipStream_t stream) {
    const float* hs    = (const float*)d_in[0];
    const float* wqkv  = (const float*)d_in[1];
    const float* bqkv  = (const float*)d_in[2];
    const float* rph   = (const float*)d_in[3];
    const float* rpw   = (const float*)d_in[4];
    const float* wproj = (const float*)d_in[5];
    const float* bproj = (const float*)d_in[6];
    float* out = (float*)d_out;

    char* ws = (char*)d_ws;
    bf16_t* x_bf   = (bf16_t*)(ws + 0);          // 38,535,168 B; reused as aout
    bf16_t* aout   = x_bf;
    bf16_t* wqkvT  = (bf16_t*)(ws + 38535168);
    bf16_t* wprojT = (bf16_t*)(ws + 42074112);
    bf16_t* qb     = (bf16_t*)(ws + 43253760);
    bf16_t* kb     = (bf16_t*)(ws + 81788928);
    bf16_t* vtb    = (bf16_t*)(ws + 120324096);  // total 161,218,560

    cast_x_kernel<<<9408, 256, 0, stream>>>(hs, x_bf);
    transpose_cast_kernel<<<dim3(72, 24), dim3(32, 8), 0, stream>>>(wqkv, wqkvT, 768, 2304);
    transpose_cast_kernel<<<dim3(24, 24), dim3(32, 8), 0, stream>>>(wproj, wprojT, 768, 768);
    qkv_gemm_kernel<<<3528, 256, 0, stream>>>(x_bf, wqkvT, bqkv, qb, kb, vtb);
    attn_kernel<<<10752, 256, 0, stream>>>(qb, kb, vtb, rph, rpw, aout);
    proj_gemm_kernel<<<1176, 256, 0, stream>>>(aout, wprojT, bproj, out);
}

// Round 4
// 489.674 us; speedup vs baseline: 1.7288x; 1.0416x over previous
//
#include <hip/hip_runtime.h>

typedef __bf16 bf16_t;
typedef __bf16 bf16x8 __attribute__((ext_vector_type(8)));
typedef float floatx4 __attribute__((ext_vector_type(4)));

#define B_    128
#define H_    14
#define HW_   196
#define C_    768
#define NH_   12
#define HD_   64
#define M_    25088
#define NQKV_ 2304
#define KDIM_ 768
#define BK_   64    // GEMM K-tile: 12 iterations over K=768, 32 MFMAs per barrier
#define VPAD_ 208   // v^T global row length (16B-aligned)
#define KSTR  72    // qs/ks/rT LDS row stride in bf16 (144B = 9x16: aligned, non-128 multiple)
#define PSTR  232   // pb LDS row stride in bf16 (464B: 16B-aligned, quad-conflict-free stores)
#define VSTR  224   // vTs LDS row stride in bf16 (7 k-steps of 32)

// ---------------------------------------------------------------- async 16B global->LDS
__device__ __forceinline__ void async_cp16(const void* g, void* l) {
    __builtin_amdgcn_global_load_lds((const __attribute__((address_space(1))) void*)g,
                                     (__attribute__((address_space(3))) void*)l, 16, 0, 0);
}

// ---------------------------------------------------------------- cast x -> bf16
__global__ __launch_bounds__(256) void cast_x_kernel(const float* __restrict__ in,
                                                     bf16_t* __restrict__ out) {
    size_t i = ((size_t)blockIdx.x * 256 + threadIdx.x) * 8;
    float4 a = *(const float4*)(in + i);
    float4 b = *(const float4*)(in + i + 4);
    bf16x8 v;
    v[0] = (bf16_t)a.x; v[1] = (bf16_t)a.y; v[2] = (bf16_t)a.z; v[3] = (bf16_t)a.w;
    v[4] = (bf16_t)b.x; v[5] = (bf16_t)b.y; v[6] = (bf16_t)b.z; v[7] = (bf16_t)b.w;
    *(bf16x8*)(out + i) = v;
}

// ------------------------------------------- transpose + cast weight (rows x cols) -> (cols x rows)
__global__ __launch_bounds__(256) void transpose_cast_kernel(const float* __restrict__ in,
                                                             bf16_t* __restrict__ out,
                                                             int rows, int cols) {
    __shared__ float tile[32][33];
    int c0 = blockIdx.x * 32, r0 = blockIdx.y * 32;
    for (int i = threadIdx.y; i < 32; i += 8) {
        int r = r0 + i, c = c0 + threadIdx.x;
        if (r < rows && c < cols) tile[i][threadIdx.x] = in[(size_t)r * cols + c];
    }
    __syncthreads();
    for (int i = threadIdx.y; i < 32; i += 8) {
        int orow = c0 + i;            // output row = input col
        int oc   = r0 + threadIdx.x;  // output col = input row
        if (orow < cols && oc < rows)
            out[(size_t)orow * rows + oc] = (bf16_t)tile[threadIdx.x][i];
    }
}

// ---------------------------------------------------------------- shared GEMM core
// A: M x 768 row-major bf16.  Bt: N x 768 row-major bf16.  128x128 tile, BK=64,
// 256 threads = 4 waves 2x2, 64x64 per wave (4x4 MFMA tiles). global_load_lds
// width=16 staging; XOR column-chunk swizzle for fragment-read bank spread.
__device__ __forceinline__ void gemm128_compute(const bf16_t* __restrict__ A,
                                                const bf16_t* __restrict__ Bt,
                                                int m0, int n0,
                                                floatx4 acc[4][4],
                                                bf16_t (*As)[BK_], bf16_t (*Bs)[BK_]) {
    const int tid  = threadIdx.x;
    const int lane = tid & 63, wave = tid >> 6;
    const int wm = (wave & 1) << 6, wn = (wave >> 1) << 6;
    const int lrow = lane & 15, quad = lane >> 4;

    #pragma unroll
    for (int i = 0; i < 4; i++)
        #pragma unroll
        for (int j = 0; j < 4; j++) acc[i][j] = (floatx4){0.f, 0.f, 0.f, 0.f};

    const int sr = tid >> 3;        // staging base row 0..31 (+ i*32)
    const int cc = tid & 7;         // LDS column chunk (16B units)

    for (int k0 = 0; k0 < KDIM_; k0 += BK_) {
        __syncthreads();
        #pragma unroll
        for (int i = 0; i < 4; i++) {
            int row  = sr + i * 32;
            int scol = ((cc ^ (row & 7)) * 8);      // swizzled source k-chunk
            async_cp16(A  + (size_t)(m0 + row) * KDIM_ + k0 + scol, &As[row][cc * 8]);
            async_cp16(Bt + (size_t)(n0 + row) * KDIM_ + k0 + scol, &Bs[row][cc * 8]);
        }
        __syncthreads();

        #pragma unroll
        for (int kh = 0; kh < 2; kh++) {
            bf16x8 af[4], bfr[4];
            #pragma unroll
            for (int i = 0; i < 4; i++) {
                int rw = wm + i * 16 + lrow;
                af[i] = *(const bf16x8*)&As[rw][((kh * 4 + quad) ^ (rw & 7)) * 8];
            }
            #pragma unroll
            for (int j = 0; j < 4; j++) {
                int rw = wn + j * 16 + lrow;
                bfr[j] = *(const bf16x8*)&Bs[rw][((kh * 4 + quad) ^ (rw & 7)) * 8];
            }
            #pragma unroll
            for (int i = 0; i < 4; i++)
                #pragma unroll
                for (int j = 0; j < 4; j++)
                    acc[i][j] = __builtin_amdgcn_mfma_f32_16x16x32_bf16(af[i], bfr[j], acc[i][j], 0, 0, 0);
        }
    }
}

// ---------------------------------------------------------------- QKV GEMM + scatter epilogue
// 1D grid 3528, L2 swizzle: 4-m-tile chunk x all 18 n-tiles per group.
// q/k epilogue: C-tile transpose through LDS -> 16B coalesced stores.
__global__ __launch_bounds__(256) void qkv_gemm_kernel(const bf16_t* __restrict__ A,
                                                       const bf16_t* __restrict__ Bt,
                                                       const float* __restrict__ bias,
                                                       bf16_t* __restrict__ qb,
                                                       bf16_t* __restrict__ kb,
                                                       bf16_t* __restrict__ vtb) {
    __shared__ __align__(16) char smem[128 * 136 * 2];   // As|Bs union Cs[128][136]
    bf16_t (*As)[BK_] = (bf16_t(*)[BK_])smem;
    bf16_t (*Bs)[BK_] = (bf16_t(*)[BK_])(smem + 128 * BK_ * 2);
    bf16_t (*Cs)[136] = (bf16_t(*)[136])smem;

    const int lin = blockIdx.x;
    const int g = lin / 72, r = lin - g * 72;
    const int m0 = (g * 4 + (r & 3)) * 128;
    const int n0 = (r >> 2) * 128;
    floatx4 acc[4][4];
    gemm128_compute(A, Bt, m0, n0, acc, As, Bs);

    const int tid = threadIdx.x;
    const int lane = tid & 63, wave = tid >> 6;
    const int wm = (wave & 1) << 6, wn = (wave >> 1) << 6;
    const int lrow = lane & 15, quad = lane >> 4;
    const int sel = n0 / C_;                     // block-uniform: 0=q 1=k 2=v

    if (sel == 2) {
        // v^T: 4 consecutive t per (i) -> one ushort4 store
        #pragma unroll
        for (int j = 0; j < 4; j++) {
            int n = n0 + wn + j * 16 + lrow;
            float bv = bias[n];
            int nc = n - 2 * C_;
            int nh = nc >> 6, hd = nc & 63;
            #pragma unroll
            for (int i = 0; i < 4; i++) {
                int m = m0 + wm + i * 16 + quad * 4;
                int b = m / HW_, t = m - b * HW_;
                int head = b * NH_ + nh;
                ushort4 pk;
                bf16_t h;
                h = (bf16_t)(acc[i][j][0] + bv); pk.x = __builtin_bit_cast(unsigned short, h);
                h = (bf16_t)(acc[i][j][1] + bv); pk.y = __builtin_bit_cast(unsigned short, h);
                h = (bf16_t)(acc[i][j][2] + bv); pk.z = __builtin_bit_cast(unsigned short, h);
                h = (bf16_t)(acc[i][j][3] + bv); pk.w = __builtin_bit_cast(unsigned short, h);
                *(ushort4*)(vtb + ((size_t)head * HD_ + hd) * VPAD_ + t) = pk;
            }
        }
    } else {
        __syncthreads();   // As/Bs reads complete before Cs overwrite
        #pragma unroll
        for (int j = 0; j < 4; j++) {
            int n = n0 + wn + j * 16 + lrow;
            float bv = bias[n];
            #pragma unroll
            for (int i = 0; i < 4; i++)
                #pragma unroll
                for (int rr = 0; rr < 4; rr++)
                    Cs[wm + i * 16 + quad * 4 + rr][wn + j * 16 + lrow] = (bf16_t)(acc[i][j][rr] + bv);
        }
        __syncthreads();
        bf16_t* dst = sel ? kb : qb;
        const int n0s = n0 - sel * C_;           // 0..639 within q/k
        #pragma unroll
        for (int u = 0; u < 8; u++) {
            int idx = tid + u * 256;             // 0..2047
            int rr = idx >> 4, c = idx & 15;     // row 0..127, 16B chunk 0..15
            int m = m0 + rr;
            int b = m / HW_, t = m - b * HW_;
            int ncol = n0s + c * 8;
            int nh = ncol >> 6, hd = ncol & 63;
            *(uint4*)(dst + (((size_t)(b * NH_ + nh)) * HW_ + t) * HD_ + hd) =
                *(const uint4*)&Cs[rr][c * 8];
        }
    }
}

// ---------------------------------------------------------------- proj GEMM + bias -> fp32 out
__global__ __launch_bounds__(256) void proj_gemm_kernel(const bf16_t* __restrict__ A,
                                                        const bf16_t* __restrict__ Bt,
                                                        const float* __restrict__ bias,
                                                        float* __restrict__ out) {
    __shared__ __align__(16) bf16_t As[128][BK_];
    __shared__ __align__(16) bf16_t Bs[128][BK_];
    const int lin = blockIdx.x;
    const int g = lin / 24, r = lin - g * 24;
    const int m0 = (g * 4 + (r & 3)) * 128;
    const int n0 = (r >> 2) * 128;
    floatx4 acc[4][4];
    gemm128_compute(A, Bt, m0, n0, acc, As, Bs);

    const int lane = threadIdx.x & 63, wave = threadIdx.x >> 6;
    const int wm = (wave & 1) << 6, wn = (wave >> 1) << 6;
    const int lrow = lane & 15, quad = lane >> 4;
    #pragma unroll
    for (int j = 0; j < 4; j++) {
        int n = n0 + wn + j * 16 + lrow;
        float bv = bias[n];
        #pragma unroll
        for (int i = 0; i < 4; i++) {
            #pragma unroll
            for (int rr = 0; rr < 4; rr++) {
                int m = m0 + wm + i * 16 + quad * 4 + rr;
                out[(size_t)m * C_ + n] = acc[i][j][rr] + bv;
            }
        }
    }
}

// ---------------------------------------------------------------- fused attention
// 1D grid 10752, XCD-partition remap. Register-resident softmax: S fragments stay
// in VGPRs; row max/sum via 16-lane butterflies + pmax/psum[2][32] cross-wave combine.
__global__ __launch_bounds__(256, 3) void attn_kernel(const bf16_t* __restrict__ qb,
                                                      const bf16_t* __restrict__ kb,
                                                      const bf16_t* __restrict__ vtb,
                                                      const float* __restrict__ rph,
                                                      const float* __restrict__ rpw,
                                                      bf16_t* __restrict__ aout) {
    const int lin = blockIdx.x;
    const int task = (lin & 7) * 1344 + (lin >> 3);
    const int head = task / 7;
    const int qt = task - head * 7;
    const int bb = head / NH_, nh = head - bb * NH_;
    const int q0 = qt * 32;
    const int tid = threadIdx.x;
    const int lane = tid & 63, wave = tid >> 6;
    const int lrow = lane & 15, quad = lane >> 4;

    __shared__ __align__(16) bf16_t qs[32][KSTR];          // 4608 B
    __shared__ __align__(16) bf16_t kvu[208 * KSTR];       // 29952 B: ks[208][72] U vTs[64][224]
    __shared__ __align__(16) bf16_t pbu[32 * PSTR];        // 14848 B: pb[32][232] U rT[64][72]
    __shared__ bf16_t QRh[32][34];                         // 2176 B each
    __shared__ bf16_t QRw[32][34];
    __shared__ float pmax[2][32], psum[2][32];             // 512 B
    // total 54,272 B -> 3 blocks/CU

    bf16_t (*ks)[KSTR]  = (bf16_t(*)[KSTR])kvu;
    bf16_t (*vTs)[VSTR] = (bf16_t(*)[VSTR])kvu;
    bf16_t (*pb)[PSTR]  = (bf16_t(*)[PSTR])pbu;
    bf16_t (*rT)[KSTR]  = (bf16_t(*)[KSTR])pbu;            // rows 0..31 rph, 32..63 rpw

    bf16x8 z;
    #pragma unroll
    for (int e = 0; e < 8; e++) z[e] = (bf16_t)0.f;

    // ---- phase 0: load q tile, rel tables (bf16), keys
    {
        int row = tid >> 3, col = (tid & 7) * 8;
        int t = q0 + row;
        *(bf16x8*)&qs[row][col] =
            (t < HW_) ? *(const bf16x8*)(qb + ((size_t)head * HW_ + t) * HD_ + col) : z;
    }
    #pragma unroll
    for (int t2 = 0; t2 < 2; t2++) {
        int u = tid * 2 + t2;              // 0..511
        int which = u >> 8, rem = u & 255;
        int l = rem >> 3, c = (rem & 7) * 8;
        bf16x8 v = z;
        if (l < 27) {
            const float* src = (which ? rpw : rph) + (size_t)l * HD_ + c;
            float4 a = *(const float4*)src;
            float4 b = *(const float4*)(src + 4);
            v[0] = (bf16_t)a.x; v[1] = (bf16_t)a.y; v[2] = (bf16_t)a.z; v[3] = (bf16_t)a.w;
            v[4] = (bf16_t)b.x; v[5] = (bf16_t)b.y; v[6] = (bf16_t)b.z; v[7] = (bf16_t)b.w;
        }
        *(bf16x8*)&rT[which * 32 + l][c] = v;
    }
    for (int v8 = tid; v8 < 208 * 8; v8 += 256) {
        int row = v8 >> 3, col = (v8 & 7) * 8;
        *(bf16x8*)&ks[row][col] =
            (row < HW_) ? *(const bf16x8*)(kb + ((size_t)head * HW_ + row) * HD_ + col) : z;
    }
    __syncthreads();                                        // B0

    // ---- phase 1: QR tables via MFMA (8 tasks over 4 waves), stored bf16
    #pragma unroll
    for (int t2 = 0; t2 < 2; t2++) {
        int tsk = wave * 2 + t2;
        int which = tsk >> 2, mi2 = (tsk >> 1) & 1, ni = tsk & 1;
        floatx4 a4 = (floatx4){0.f, 0.f, 0.f, 0.f};
        #pragma unroll
        for (int kk = 0; kk < 2; kk++) {
            bf16x8 af  = *(const bf16x8*)&qs[mi2 * 16 + lrow][kk * 32 + quad * 8];
            bf16x8 bf8 = *(const bf16x8*)&rT[which * 32 + ni * 16 + lrow][kk * 32 + quad * 8];
            a4 = __builtin_amdgcn_mfma_f32_16x16x32_bf16(af, bf8, a4, 0, 0, 0);
        }
        int l = ni * 16 + lrow;
        if (l < 27) {
            bf16_t (*QR)[34] = which ? QRw : QRh;
            #pragma unroll
            for (int rr = 0; rr < 4; rr++) QR[mi2 * 16 + quad * 4 + rr][l] = (bf16_t)a4[rr];
        }
    }
    __syncthreads();                                        // B1 (rT dead, QR ready)

    // pb pad cols 208..231 zeroed (rT region dead now)
    if (tid < 96) {
        int row = tid / 3, col = 208 + (tid % 3) * 8;
        *(bf16x8*)&pb[row][col] = z;
    }

    // ---- phase 2: S fragments in registers (wave wh covers jt = 2t+wh)
    const int wh = wave >> 1, mi = wave & 1;
    const int NT = 7 - wh;                                  // 7 or 6 jt tiles
    float sv[7][4];
    float m4[4] = {-1e30f, -1e30f, -1e30f, -1e30f};
    int hq[4], wq[4];
    #pragma unroll
    for (int rr = 0; rr < 4; rr++) {
        int t = q0 + mi * 16 + quad * 4 + rr;
        hq[rr] = t / 14; wq[rr] = t - hq[rr] * 14;
    }
    for (int t = 0; t < NT; t++) {
        int jt = 2 * t + wh;
        floatx4 a4 = (floatx4){0.f, 0.f, 0.f, 0.f};
        #pragma unroll
        for (int kk = 0; kk < 2; kk++) {
            bf16x8 af  = *(const bf16x8*)&qs[mi * 16 + lrow][kk * 32 + quad * 8];
            bf16x8 bf8 = *(const bf16x8*)&ks[jt * 16 + lrow][kk * 32 + quad * 8];
            a4 = __builtin_amdgcn_mfma_f32_16x16x32_bf16(af, bf8, a4, 0, 0, 0);
        }
        int n = jt * 16 + lrow;
        if (n < HW_) {
            int kh = n / 14, kw = n - kh * 14;
            #pragma unroll
            for (int rr = 0; rr < 4; rr++) {
                int qi = mi * 16 + quad * 4 + rr;
                float s = a4[rr] * 0.125f + (float)QRh[qi][hq[rr] - kh + 13]
                                          + (float)QRw[qi][wq[rr] - kw + 13];
                sv[t][rr] = s;
                m4[rr] = fmaxf(m4[rr], s);
            }
        } else {
            #pragma unroll
            for (int rr = 0; rr < 4; rr++) sv[t][rr] = -1e30f;
        }
    }
    // row-max butterfly across the 16 col-lanes
    #pragma unroll
    for (int off = 1; off < 16; off <<= 1)
        #pragma unroll
        for (int rr = 0; rr < 4; rr++) m4[rr] = fmaxf(m4[rr], __shfl_xor(m4[rr], off));
    if (lrow == 0)
        #pragma unroll
        for (int rr = 0; rr < 4; rr++) pmax[wh][mi * 16 + quad * 4 + rr] = m4[rr];
    __syncthreads();                                        // B2 (ks dead, pmax ready)

    // ---- phase 3: v^T global loads (into regs; LDS write after exp math)
    bf16x8 vstage[7];
    int vrow[7], vcol[7];
    #pragma unroll
    for (int i = 0; i < 7; i++) {
        int v8 = tid + i * 256;
        vrow[i] = v8 / 28;
        int c8 = v8 - vrow[i] * 28;
        vcol[i] = c8 * 8;
        vstage[i] = (vcol[i] < VPAD_)
            ? *(const bf16x8*)(vtb + ((size_t)head * HD_ + vrow[i]) * VPAD_ + vcol[i]) : z;
    }

    // exp + unnormalized P -> pb, per-row partial sums
    float mxr[4], s4[4] = {0.f, 0.f, 0.f, 0.f};
    #pragma unroll
    for (int rr = 0; rr < 4; rr++) {
        int qi = mi * 16 + quad * 4 + rr;
        mxr[rr] = fmaxf(pmax[0][qi], pmax[1][qi]);
    }
    for (int t = 0; t < NT; t++) {
        int n = (2 * t + wh) * 16 + lrow;
        #pragma unroll
        for (int rr = 0; rr < 4; rr++) {
            float e = __expf(sv[t][rr] - mxr[rr]);
            s4[rr] += e;
            pb[mi * 16 + quad * 4 + rr][n] = (bf16_t)e;
        }
    }
    #pragma unroll
    for (int off = 1; off < 16; off <<= 1)
        #pragma unroll
        for (int rr = 0; rr < 4; rr++) s4[rr] += __shfl_xor(s4[rr], off);
    if (lrow == 0)
        #pragma unroll
        for (int rr = 0; rr < 4; rr++) psum[wh][mi * 16 + quad * 4 + rr] = s4[rr];

    // commit v^T to LDS (kvu region)
    #pragma unroll
    for (int i = 0; i < 7; i++) *(bf16x8*)&vTs[vrow[i]][vcol[i]] = vstage[i];
    __syncthreads();                                        // B3 (pb, vTs, psum ready)

    // ---- phase 4: O = P @ V  (2 mi x 4 jt over 4 waves; K = 224 = 7 steps)
    const int j2 = wh * 2;
    #pragma unroll
    for (int jj = 0; jj < 2; jj++) {
        int jt = j2 + jj;
        floatx4 a4 = (floatx4){0.f, 0.f, 0.f, 0.f};
        #pragma unroll
        for (int kk = 0; kk < 7; kk++) {
            bf16x8 af  = *(const bf16x8*)&pb[mi * 16 + lrow][kk * 32 + quad * 8];
            bf16x8 bf8 = *(const bf16x8*)&vTs[jt * 16 + lrow][kk * 32 + quad * 8];
            a4 = __builtin_amdgcn_mfma_f32_16x16x32_bf16(af, bf8, a4, 0, 0, 0);
        }
        int col = nh * HD_ + jt * 16 + lrow;
        #pragma unroll
        for (int rr = 0; rr < 4; rr++) {
            int m = mi * 16 + quad * 4 + rr;
            int t = q0 + m;
            if (t < HW_) {
                float inv = 1.f / (psum[0][m] + psum[1][m]);
                aout[((size_t)bb * HW_ + t) * C_ + col] = (bf16_t)(a4[rr] * inv);
            }
        }
    }
}

// ---------------------------------------------------------------- launcher
extern "C" void kernel_launch(void* const* d_in, const int* in_sizes, int n_in,
                              void* d_out, int out_size, void* d_ws, size_t ws_size,
                              hipStream_t stream) {
    const float* hs    = (const float*)d_in[0];
    const float* wqkv  = (const float*)d_in[1];
    const float* bqkv  = (const float*)d_in[2];
    const float* rph   = (const float*)d_in[3];
    const float* rpw   = (const float*)d_in[4];
    const float* wproj = (const float*)d_in[5];
    const float* bproj = (const float*)d_in[6];
    float* out = (float*)d_out;

    char* ws = (char*)d_ws;
    bf16_t* x_bf   = (bf16_t*)(ws + 0);          // 38,535,168 B; reused as aout
    bf16_t* aout   = x_bf;
    bf16_t* wqkvT  = (bf16_t*)(ws + 38535168);
    bf16_t* wprojT = (bf16_t*)(ws + 42074112);
    bf16_t* qb     = (bf16_t*)(ws + 43253760);
    bf16_t* kb     = (bf16_t*)(ws + 81788928);
    bf16_t* vtb    = (bf16_t*)(ws + 120324096);  // total 161,218,560

    cast_x_kernel<<<9408, 256, 0, stream>>>(hs, x_bf);
    transpose_cast_kernel<<<dim3(72, 24), dim3(32, 8), 0, stream>>>(wqkv, wqkvT, 768, 2304);
    transpose_cast_kernel<<<dim3(24, 24), dim3(32, 8), 0, stream>>>(wproj, wprojT, 768, 768);
    qkv_gemm_kernel<<<3528, 256, 0, stream>>>(x_bf, wqkvT, bqkv, qb, kb, vtb);
    attn_kernel<<<10752, 256, 0, stream>>>(qb, kb, vtb, rph, rpw, aout);
    proj_gemm_kernel<<<1176, 256, 0, stream>>>(aout, wprojT, bproj, out);
}

// Round 5
// 483.990 us; speedup vs baseline: 1.7491x; 1.0117x over previous
//
#include <hip/hip_runtime.h>

typedef __bf16 bf16_t;
typedef __bf16 bf16x8 __attribute__((ext_vector_type(8)));
typedef float floatx4 __attribute__((ext_vector_type(4)));

#define B_    128
#define H_    14
#define HW_   196
#define C_    768
#define NH_   12
#define HD_   64
#define M_    25088
#define NQKV_ 2304
#define KDIM_ 768
#define BK_   64    // GEMM K-tile
#define VPAD_ 208   // v^T global row length (16B-aligned)
#define RSTR  72    // rT staging stride (bf16)
#define QSTR  104   // q'/k' augmented row stride in bf16 (208B = 13x16B, odd 16B count -> bank spread)
#define PSTR  232   // pb LDS row stride in bf16
#define VSTR  224   // vTs LDS row stride in bf16 (7 k-steps of 32)

// ---------------------------------------------------------------- async 16B global->LDS
__device__ __forceinline__ void async_cp16(const void* g, void* l) {
    __builtin_amdgcn_global_load_lds((const __attribute__((address_space(1))) void*)g,
                                     (__attribute__((address_space(3))) void*)l, 16, 0, 0);
}

// ---------------------------------------------------------------- cast x -> bf16
__global__ __launch_bounds__(256) void cast_x_kernel(const float* __restrict__ in,
                                                     bf16_t* __restrict__ out) {
    size_t i = ((size_t)blockIdx.x * 256 + threadIdx.x) * 8;
    float4 a = *(const float4*)(in + i);
    float4 b = *(const float4*)(in + i + 4);
    bf16x8 v;
    v[0] = (bf16_t)a.x; v[1] = (bf16_t)a.y; v[2] = (bf16_t)a.z; v[3] = (bf16_t)a.w;
    v[4] = (bf16_t)b.x; v[5] = (bf16_t)b.y; v[6] = (bf16_t)b.z; v[7] = (bf16_t)b.w;
    *(bf16x8*)(out + i) = v;
}

// ------------------------------------------- transpose + cast weight (rows x cols) -> (cols x rows)
__global__ __launch_bounds__(256) void transpose_cast_kernel(const float* __restrict__ in,
                                                             bf16_t* __restrict__ out,
                                                             int rows, int cols) {
    __shared__ float tile[32][33];
    int c0 = blockIdx.x * 32, r0 = blockIdx.y * 32;
    for (int i = threadIdx.y; i < 32; i += 8) {
        int r = r0 + i, c = c0 + threadIdx.x;
        if (r < rows && c < cols) tile[i][threadIdx.x] = in[(size_t)r * cols + c];
    }
    __syncthreads();
    for (int i = threadIdx.y; i < 32; i += 8) {
        int orow = c0 + i;            // output row = input col
        int oc   = r0 + threadIdx.x;  // output col = input row
        if (orow < cols && oc < rows)
            out[(size_t)orow * rows + oc] = (bf16_t)tile[threadIdx.x][i];
    }
}

// ---------------------------------------------------------------- shared GEMM core
__device__ __forceinline__ void gemm128_compute(const bf16_t* __restrict__ A,
                                                const bf16_t* __restrict__ Bt,
                                                int m0, int n0,
                                                floatx4 acc[4][4],
                                                bf16_t (*As)[BK_], bf16_t (*Bs)[BK_]) {
    const int tid  = threadIdx.x;
    const int lane = tid & 63, wave = tid >> 6;
    const int wm = (wave & 1) << 6, wn = (wave >> 1) << 6;
    const int lrow = lane & 15, quad = lane >> 4;

    #pragma unroll
    for (int i = 0; i < 4; i++)
        #pragma unroll
        for (int j = 0; j < 4; j++) acc[i][j] = (floatx4){0.f, 0.f, 0.f, 0.f};

    const int sr = tid >> 3;        // staging base row 0..31 (+ i*32)
    const int cc = tid & 7;         // LDS column chunk (16B units)

    for (int k0 = 0; k0 < KDIM_; k0 += BK_) {
        __syncthreads();
        #pragma unroll
        for (int i = 0; i < 4; i++) {
            int row  = sr + i * 32;
            int scol = ((cc ^ (row & 7)) * 8);      // swizzled source k-chunk
            async_cp16(A  + (size_t)(m0 + row) * KDIM_ + k0 + scol, &As[row][cc * 8]);
            async_cp16(Bt + (size_t)(n0 + row) * KDIM_ + k0 + scol, &Bs[row][cc * 8]);
        }
        __syncthreads();

        #pragma unroll
        for (int kh = 0; kh < 2; kh++) {
            bf16x8 af[4], bfr[4];
            #pragma unroll
            for (int i = 0; i < 4; i++) {
                int rw = wm + i * 16 + lrow;
                af[i] = *(const bf16x8*)&As[rw][((kh * 4 + quad) ^ (rw & 7)) * 8];
            }
            #pragma unroll
            for (int j = 0; j < 4; j++) {
                int rw = wn + j * 16 + lrow;
                bfr[j] = *(const bf16x8*)&Bs[rw][((kh * 4 + quad) ^ (rw & 7)) * 8];
            }
            #pragma unroll
            for (int i = 0; i < 4; i++)
                #pragma unroll
                for (int j = 0; j < 4; j++)
                    acc[i][j] = __builtin_amdgcn_mfma_f32_16x16x32_bf16(af[i], bfr[j], acc[i][j], 0, 0, 0);
        }
    }
}

// ---------------------------------------------------------------- QKV GEMM + scatter epilogue
// q written pre-scaled by 0.125 (softmax scale folded in).
__global__ __launch_bounds__(256) void qkv_gemm_kernel(const bf16_t* __restrict__ A,
                                                       const bf16_t* __restrict__ Bt,
                                                       const float* __restrict__ bias,
                                                       bf16_t* __restrict__ qb,
                                                       bf16_t* __restrict__ kb,
                                                       bf16_t* __restrict__ vtb) {
    __shared__ __align__(16) char smem[128 * 136 * 2];   // As|Bs union Cs[128][136]
    bf16_t (*As)[BK_] = (bf16_t(*)[BK_])smem;
    bf16_t (*Bs)[BK_] = (bf16_t(*)[BK_])(smem + 128 * BK_ * 2);
    bf16_t (*Cs)[136] = (bf16_t(*)[136])smem;

    const int lin = blockIdx.x;
    const int g = lin / 72, r = lin - g * 72;
    const int m0 = (g * 4 + (r & 3)) * 128;
    const int n0 = (r >> 2) * 128;
    floatx4 acc[4][4];
    gemm128_compute(A, Bt, m0, n0, acc, As, Bs);

    const int tid = threadIdx.x;
    const int lane = tid & 63, wave = tid >> 6;
    const int wm = (wave & 1) << 6, wn = (wave >> 1) << 6;
    const int lrow = lane & 15, quad = lane >> 4;
    const int sel = n0 / C_;                     // block-uniform: 0=q 1=k 2=v

    if (sel == 2) {
        #pragma unroll
        for (int j = 0; j < 4; j++) {
            int n = n0 + wn + j * 16 + lrow;
            float bv = bias[n];
            int nc = n - 2 * C_;
            int nh = nc >> 6, hd = nc & 63;
            #pragma unroll
            for (int i = 0; i < 4; i++) {
                int m = m0 + wm + i * 16 + quad * 4;
                int b = m / HW_, t = m - b * HW_;
                int head = b * NH_ + nh;
                ushort4 pk;
                bf16_t h;
                h = (bf16_t)(acc[i][j][0] + bv); pk.x = __builtin_bit_cast(unsigned short, h);
                h = (bf16_t)(acc[i][j][1] + bv); pk.y = __builtin_bit_cast(unsigned short, h);
                h = (bf16_t)(acc[i][j][2] + bv); pk.z = __builtin_bit_cast(unsigned short, h);
                h = (bf16_t)(acc[i][j][3] + bv); pk.w = __builtin_bit_cast(unsigned short, h);
                *(ushort4*)(vtb + ((size_t)head * HD_ + hd) * VPAD_ + t) = pk;
            }
        }
    } else {
        const float sc = (sel == 0) ? 0.125f : 1.0f;   // fold softmax scale into q
        __syncthreads();   // As/Bs reads complete before Cs overwrite
        #pragma unroll
        for (int j = 0; j < 4; j++) {
            int n = n0 + wn + j * 16 + lrow;
            float bv = bias[n];
            #pragma unroll
            for (int i = 0; i < 4; i++)
                #pragma unroll
                for (int rr = 0; rr < 4; rr++)
                    Cs[wm + i * 16 + quad * 4 + rr][wn + j * 16 + lrow] =
                        (bf16_t)((acc[i][j][rr] + bv) * sc);
        }
        __syncthreads();
        bf16_t* dst = sel ? kb : qb;
        const int n0s = n0 - sel * C_;
        #pragma unroll
        for (int u = 0; u < 8; u++) {
            int idx = tid + u * 256;
            int rr = idx >> 4, c = idx & 15;
            int m = m0 + rr;
            int b = m / HW_, t = m - b * HW_;
            int ncol = n0s + c * 8;
            int nh = ncol >> 6, hd = ncol & 63;
            *(uint4*)(dst + (((size_t)(b * NH_ + nh)) * HW_ + t) * HD_ + hd) =
                *(const uint4*)&Cs[rr][c * 8];
        }
    }
}

// ---------------------------------------------------------------- proj GEMM + bias -> fp32 out
__global__ __launch_bounds__(256) void proj_gemm_kernel(const bf16_t* __restrict__ A,
                                                        const bf16_t* __restrict__ Bt,
                                                        const float* __restrict__ bias,
                                                        float* __restrict__ out) {
    __shared__ __align__(16) bf16_t As[128][BK_];
    __shared__ __align__(16) bf16_t Bs[128][BK_];
    const int lin = blockIdx.x;
    const int g = lin / 24, r = lin - g * 24;
    const int m0 = (g * 4 + (r & 3)) * 128;
    const int n0 = (r >> 2) * 128;
    floatx4 acc[4][4];
    gemm128_compute(A, Bt, m0, n0, acc, As, Bs);

    const int lane = threadIdx.x & 63, wave = threadIdx.x >> 6;
    const int wm = (wave & 1) << 6, wn = (wave >> 1) << 6;
    const int lrow = lane & 15, quad = lane >> 4;
    #pragma unroll
    for (int j = 0; j < 4; j++) {
        int n = n0 + wn + j * 16 + lrow;
        float bv = bias[n];
        #pragma unroll
        for (int i = 0; i < 4; i++) {
            #pragma unroll
            for (int rr = 0; rr < 4; rr++) {
                int m = m0 + wm + i * 16 + quad * 4 + rr;
                out[(size_t)m * C_ + n] = acc[i][j][rr] + bv;
            }
        }
    }
}

// ---------------------------------------------------------------- fused attention
// Augmented-K formulation: q' = [0.125q | QRh gather | QRw gather | 0] (96 cols),
// k' = [k | onehot14(kh) | onehot14(kw) | 0]; S = q'.k' in one MFMA chain (3 k-steps).
// PV computes O^T (A=V^T, B=P) so output stores are packed ushort4.
__global__ __launch_bounds__(256, 3) void attn_kernel(const bf16_t* __restrict__ qb,
                                                      const bf16_t* __restrict__ kb,
                                                      const bf16_t* __restrict__ vtb,
                                                      const float* __restrict__ rph,
                                                      const float* __restrict__ rpw,
                                                      bf16_t* __restrict__ aout) {
    const int lin = blockIdx.x;
    const int task = (lin & 7) * 1344 + (lin >> 3);
    const int head = task / 7;
    const int qt = task - head * 7;
    const int bb = head / NH_, nh = head - bb * NH_;
    const int q0 = qt * 32;
    const int tid = threadIdx.x;
    const int lane = tid & 63, wave = tid >> 6;
    const int lrow = lane & 15, quad = lane >> 4;

    __shared__ __align__(16) bf16_t qs[32][QSTR];          // 6656 B  (q')
    __shared__ __align__(16) bf16_t kvu[208 * QSTR];       // 43264 B: ks'[208][104] U vTs[64][224]
    __shared__ __align__(16) bf16_t pbu[32 * PSTR];        // 14848 B: pb[32][232] U rT[64][72]
    __shared__ bf16_t QRh[32][34];                         // 2176 B each
    __shared__ bf16_t QRw[32][34];
    __shared__ float pmax[2][32], psum[2][32];             // 512 B
    // total 69,632 B

    bf16_t (*ks)[QSTR]  = (bf16_t(*)[QSTR])kvu;
    bf16_t (*vTs)[VSTR] = (bf16_t(*)[VSTR])kvu;
    bf16_t (*pb)[PSTR]  = (bf16_t(*)[PSTR])pbu;
    bf16_t (*rT)[RSTR]  = (bf16_t(*)[RSTR])pbu;            // rows 0..31 rph, 32..63 rpw

    bf16x8 z;
    #pragma unroll
    for (int e = 0; e < 8; e++) z[e] = (bf16_t)0.f;

    // ---- phase 0: stage q (cols 0..63), rel tables, k' (data + zeros + one-hots)
    {
        int row = tid >> 3, col = (tid & 7) * 8;
        int t = q0 + row;
        *(bf16x8*)&qs[row][col] =
            (t < HW_) ? *(const bf16x8*)(qb + ((size_t)head * HW_ + t) * HD_ + col) : z;
    }
    #pragma unroll
    for (int t2 = 0; t2 < 2; t2++) {
        int u = tid * 2 + t2;              // 0..511
        int which = u >> 8, rem = u & 255;
        int l = rem >> 3, c = (rem & 7) * 8;
        bf16x8 v = z;
        if (l < 27) {
            const float* src = (which ? rpw : rph) + (size_t)l * HD_ + c;
            float4 a = *(const float4*)src;
            float4 b = *(const float4*)(src + 4);
            v[0] = (bf16_t)a.x; v[1] = (bf16_t)a.y; v[2] = (bf16_t)a.z; v[3] = (bf16_t)a.w;
            v[4] = (bf16_t)b.x; v[5] = (bf16_t)b.y; v[6] = (bf16_t)b.z; v[7] = (bf16_t)b.w;
        }
        *(bf16x8*)&rT[which * 32 + l][c] = v;
    }
    for (int v8 = tid; v8 < 208 * 8; v8 += 256) {          // k data cols 0..63
        int row = v8 >> 3, col = (v8 & 7) * 8;
        *(bf16x8*)&ks[row][col] =
            (row < HW_) ? *(const bf16x8*)(kb + ((size_t)head * HW_ + row) * HD_ + col) : z;
    }
    for (int u = tid; u < 208 * 5; u += 256) {             // zero cols 64..103
        int row = u / 5, c = u - row * 5;
        *(bf16x8*)&ks[row][64 + c * 8] = z;
    }
    __syncthreads();                                        // B0 (zeros visible before one-hots)
    if (tid < 208 && tid < HW_) {                          // one-hots (valid keys only)
        int kh = tid / 14, kw = tid - kh * 14;
        ks[tid][64 + kh] = (bf16_t)1.0f;
        ks[tid][78 + kw] = (bf16_t)1.0f;
    }

    // ---- phase 1: QR tables via MFMA (8 tasks over 4 waves); x8 compensates q pre-scale
    #pragma unroll
    for (int t2 = 0; t2 < 2; t2++) {
        int tsk = wave * 2 + t2;
        int which = tsk >> 2, mi2 = (tsk >> 1) & 1, ni = tsk & 1;
        floatx4 a4 = (floatx4){0.f, 0.f, 0.f, 0.f};
        #pragma unroll
        for (int kk = 0; kk < 2; kk++) {
            bf16x8 af  = *(const bf16x8*)&qs[mi2 * 16 + lrow][kk * 32 + quad * 8];
            bf16x8 bf8 = *(const bf16x8*)&rT[which * 32 + ni * 16 + lrow][kk * 32 + quad * 8];
            a4 = __builtin_amdgcn_mfma_f32_16x16x32_bf16(af, bf8, a4, 0, 0, 0);
        }
        int l = ni * 16 + lrow;
        if (l < 27) {
            bf16_t (*QR)[34] = which ? QRw : QRh;
            #pragma unroll
            for (int rr = 0; rr < 4; rr++) QR[mi2 * 16 + quad * 4 + rr][l] = (bf16_t)(a4[rr] * 8.f);
        }
    }
    __syncthreads();                                        // B1 (rT dead, QR ready)

    // ---- build q' gather cols 64..95 (from QR tables); zero pb pad cols 208..231
    for (int u = tid; u < 1024; u += 256) {
        int row = u >> 5, kk = u & 31;
        int t = q0 + row;
        int h = t / 14, w = t - h * 14;
        bf16_t val = (bf16_t)0.f;
        if (kk < 14)      val = QRh[row][h - kk + 13];
        else if (kk < 28) val = QRw[row][w - (kk - 14) + 13];
        qs[row][64 + kk] = val;
    }
    if (tid < 96) {
        int row = tid / 3, col = 208 + (tid % 3) * 8;
        *(bf16x8*)&pb[row][col] = z;
    }
    __syncthreads();                                        // B2 (q' ready)

    // ---- phase 3-early: v^T global loads into regs (overlap with S MFMAs)
    bf16x8 vstage[7];
    int vrow[7], vcol[7];
    #pragma unroll
    for (int i = 0; i < 7; i++) {
        int v8 = tid + i * 256;
        vrow[i] = v8 / 28;
        int c8 = v8 - vrow[i] * 28;
        vcol[i] = c8 * 8;
        vstage[i] = (vcol[i] < VPAD_)
            ? *(const bf16x8*)(vtb + ((size_t)head * HD_ + vrow[i]) * VPAD_ + vcol[i]) : z;
    }

    // ---- phase 2: S = q'.k' fragments in registers (wave wh covers jt = 2t+wh)
    const int wh = wave >> 1, mi = wave & 1;
    const int NT = 7 - wh;                                  // 7 or 6 jt tiles
    float sv[7][4];
    float m4[4] = {-1e30f, -1e30f, -1e30f, -1e30f};
    for (int t = 0; t < NT; t++) {
        int jt = 2 * t + wh;
        floatx4 a4 = (floatx4){0.f, 0.f, 0.f, 0.f};
        #pragma unroll
        for (int kk = 0; kk < 3; kk++) {
            bf16x8 af  = *(const bf16x8*)&qs[mi * 16 + lrow][kk * 32 + quad * 8];
            bf16x8 bf8 = *(const bf16x8*)&ks[jt * 16 + lrow][kk * 32 + quad * 8];
            a4 = __builtin_amdgcn_mfma_f32_16x16x32_bf16(af, bf8, a4, 0, 0, 0);
        }
        int n = jt * 16 + lrow;
        bool valid = (n < HW_);
        #pragma unroll
        for (int rr = 0; rr < 4; rr++) {
            float s = valid ? a4[rr] : -1e30f;
            sv[t][rr] = s;
            m4[rr] = fmaxf(m4[rr], s);
        }
    }
    #pragma unroll
    for (int off = 1; off < 16; off <<= 1)
        #pragma unroll
        for (int rr = 0; rr < 4; rr++) m4[rr] = fmaxf(m4[rr], __shfl_xor(m4[rr], off));
    if (lrow == 0)
        #pragma unroll
        for (int rr = 0; rr < 4; rr++) pmax[wh][mi * 16 + quad * 4 + rr] = m4[rr];
    __syncthreads();                                        // B3 (ks dead, pmax ready)

    // ---- exp -> unnormalized P in pb; per-row partial sums; commit v^T
    float mxr[4], s4[4] = {0.f, 0.f, 0.f, 0.f};
    #pragma unroll
    for (int rr = 0; rr < 4; rr++) {
        int qi = mi * 16 + quad * 4 + rr;
        mxr[rr] = fmaxf(pmax[0][qi], pmax[1][qi]);
    }
    for (int t = 0; t < NT; t++) {
        int n = (2 * t + wh) * 16 + lrow;
        #pragma unroll
        for (int rr = 0; rr < 4; rr++) {
            float e = __expf(sv[t][rr] - mxr[rr]);
            s4[rr] += e;
            pb[mi * 16 + quad * 4 + rr][n] = (bf16_t)e;
        }
    }
    #pragma unroll
    for (int off = 1; off < 16; off <<= 1)
        #pragma unroll
        for (int rr = 0; rr < 4; rr++) s4[rr] += __shfl_xor(s4[rr], off);
    if (lrow == 0)
        #pragma unroll
        for (int rr = 0; rr < 4; rr++) psum[wh][mi * 16 + quad * 4 + rr] = s4[rr];
    #pragma unroll
    for (int i = 0; i < 7; i++) *(bf16x8*)&vTs[vrow[i]][vcol[i]] = vstage[i];
    __syncthreads();                                        // B4 (pb, vTs, psum ready)

    // ---- phase 4: O^T = V^T @ P  (A=vTs rows [hd], B=pb rows [qi]) -> packed stores
    const int qit = wave & 1;
    const int qrow = qit * 16 + lrow;
    const float inv = 1.f / (psum[0][qrow] + psum[1][qrow]);
    const int t_out = q0 + qrow;
    #pragma unroll
    for (int jj = 0; jj < 2; jj++) {
        int hdt = (wave >> 1) * 2 + jj;
        floatx4 a4 = (floatx4){0.f, 0.f, 0.f, 0.f};
        #pragma unroll
        for (int kk = 0; kk < 7; kk++) {
            bf16x8 af  = *(const bf16x8*)&vTs[hdt * 16 + lrow][kk * 32 + quad * 8];
            bf16x8 bf8 = *(const bf16x8*)&pb[qit * 16 + lrow][kk * 32 + quad * 8];
            a4 = __builtin_amdgcn_mfma_f32_16x16x32_bf16(af, bf8, a4, 0, 0, 0);
        }
        if (t_out < HW_) {
            int col = nh * HD_ + hdt * 16 + quad * 4;
            ushort4 pk;
            bf16_t hv;
            hv = (bf16_t)(a4[0] * inv); pk.x = __builtin_bit_cast(unsigned short, hv);
            hv = (bf16_t)(a4[1] * inv); pk.y = __builtin_bit_cast(unsigned short, hv);
            hv = (bf16_t)(a4[2] * inv); pk.z = __builtin_bit_cast(unsigned short, hv);
            hv = (bf16_t)(a4[3] * inv); pk.w = __builtin_bit_cast(unsigned short, hv);
            *(ushort4*)(aout + ((size_t)bb * HW_ + t_out) * C_ + col) = pk;
        }
    }
}

// ---------------------------------------------------------------- launcher
extern "C" void kernel_launch(void* const* d_in, const int* in_sizes, int n_in,
                              void* d_out, int out_size, void* d_ws, size_t ws_size,
                              hipStream_t stream) {
    const float* hs    = (const float*)d_in[0];
    const float* wqkv  = (const float*)d_in[1];
    const float* bqkv  = (const float*)d_in[2];
    const float* rph   = (const float*)d_in[3];
    const float* rpw   = (const float*)d_in[4];
    const float* wproj = (const float*)d_in[5];
    const float* bproj = (const float*)d_in[6];
    float* out = (float*)d_out;

    char* ws = (char*)d_ws;
    bf16_t* x_bf   = (bf16_t*)(ws + 0);          // 38,535,168 B; reused as aout
    bf16_t* aout   = x_bf;
    bf16_t* wqkvT  = (bf16_t*)(ws + 38535168);
    bf16_t* wprojT = (bf16_t*)(ws + 42074112);
    bf16_t* qb     = (bf16_t*)(ws + 43253760);
    bf16_t* kb     = (bf16_t*)(ws + 81788928);
    bf16_t* vtb    = (bf16_t*)(ws + 120324096);  // total 161,218,560

    cast_x_kernel<<<9408, 256, 0, stream>>>(hs, x_bf);
    transpose_cast_kernel<<<dim3(72, 24), dim3(32, 8), 0, stream>>>(wqkv, wqkvT, 768, 2304);
    transpose_cast_kernel<<<dim3(24, 24), dim3(32, 8), 0, stream>>>(wproj, wprojT, 768, 768);
    qkv_gemm_kernel<<<3528, 256, 0, stream>>>(x_bf, wqkvT, bqkv, qb, kb, vtb);
    attn_kernel<<<10752, 256, 0, stream>>>(qb, kb, vtb, rph, rpw, aout);
    proj_gemm_kernel<<<1176, 256, 0, stream>>>(aout, wprojT, bproj, out);
}